// Round 8
// baseline (245.982 us; speedup 1.0000x reference)
//
#include <hip/hip_runtime.h>
#include <math.h>

#define BB 32
#define LL 2048
#define DD 64
#define UU 40
#define CC 64            // bf16-phase candidates per batch
#define FSEG 16          // epilogue/rescue key segments (128 keys each)
#define PSTR 42          // pT row stride (floats); even -> 8B-aligned b64 ops
#define NEG_BIG (-3.0e38f)

typedef __attribute__((ext_vector_type(8))) short short8;
typedef __attribute__((ext_vector_type(4))) float f32x4;
typedef unsigned long long ull;
typedef unsigned int uint;
typedef unsigned short ushort_t;

__device__ __forceinline__ unsigned short f2bf(float f) {
  uint u = __float_as_uint(f);
  u += 0x7FFFu + ((u >> 16) & 1u);   // RNE
  return (unsigned short)(u >> 16);
}
__device__ __forceinline__ uint fsort(float f) {
  uint u = __float_as_uint(f);
  return (u & 0x80000000u) ? ~u : (u | 0x80000000u);  // monotonic map
}
__device__ __forceinline__ ull shfl_xor_u64(ull x, int m) {
  uint lo = (uint)x, hi = (uint)(x >> 32);
  lo = __shfl_xor(lo, m);
  hi = __shfl_xor(hi, m);
  return ((ull)hi << 32) | lo;
}
__device__ __forceinline__ int4 pack_bf16x8(float4 a, float4 c4) {
  int4 o;
  o.x = (int)(f2bf(a.x) | ((uint)f2bf(a.y) << 16));
  o.y = (int)(f2bf(a.z) | ((uint)f2bf(a.w) << 16));
  o.z = (int)(f2bf(c4.x) | ((uint)f2bf(c4.y) << 16));
  o.w = (int)(f2bf(c4.z) | ((uint)f2bf(c4.w) << 16));
  return o;
}

// ---------------------------------------------------------------------------
// Kernel 1: gathered K -> bf16 (Kg) + partial Ksum (Kpart) in one pass.
// ---------------------------------------------------------------------------
__global__ __launch_bounds__(256) void prep_ksum_kernel(const float* __restrict__ K,
                                                        const int* __restrict__ idx,
                                                        ushort_t* __restrict__ Kg,
                                                        float* __restrict__ Kpart) {
  int p = blockIdx.x, b = blockIdx.y, t = threadIdx.x;
  int g = t & 7;  // 16B group = 8 elements
  float4 sa = {0.f, 0.f, 0.f, 0.f}, sb = {0.f, 0.f, 0.f, 0.f};
#pragma unroll
  for (int it = 0; it < 4; ++it) {
    int r = p * 128 + it * 32 + (t >> 3);
    int gk = idx[r];
    const float* src = K + ((size_t)b * LL + gk) * DD + g * 8;
    float4 a = *(const float4*)src;
    float4 c4 = *(const float4*)(src + 4);
    sa.x += a.x; sa.y += a.y; sa.z += a.z; sa.w += a.w;
    sb.x += c4.x; sb.y += c4.y; sb.z += c4.z; sb.w += c4.w;
    *(int4*)(Kg + ((size_t)b * LL + r) * DD + g * 8) = pack_bf16x8(a, c4);
  }
  __shared__ float red[32][64];
  int rt = t >> 3;
  *(float4*)&red[rt][g * 8] = sa;
  *(float4*)&red[rt][g * 8 + 4] = sb;
  __syncthreads();
  if (t < 64) {
    float s = 0.f;
#pragma unroll
    for (int r = 0; r < 32; ++r) s += red[r][t];
    Kpart[(b * 16 + p) * 64 + t] = s;
  }
}

// ---------------------------------------------------------------------------
// Kernel 2: bf16 MFMA M-scores, SPLIT-K (2 halves of 1024 sampled keys).
// grid (16 qtiles x 2 halves, B) = 1024 blocks -> 4 blocks/CU resident.
// Register-prefetch of next K-chunk overlaps global latency with MFMA.
// Writes raw max -> Mhalf[b][h][q]; h==0 block also writes mean term
// -> Mmean[b][q] (fp32, identical code to r7's tail). max is exactly
// associative -> candidate set bit-identical to unsplit version.
// ---------------------------------------------------------------------------
__global__ __launch_bounds__(256) void mfma_m_kernel(const float* __restrict__ Q,
                                                     const ushort_t* __restrict__ Kg,
                                                     const float* __restrict__ Kpart,
                                                     float* __restrict__ Mhalf,
                                                     float* __restrict__ Mmean) {
  __shared__ __align__(16) ushort_t Qs[128 * 64];  // 16 KB, swizzled
  __shared__ __align__(16) ushort_t Ks[128 * 64];  // 16 KB, swizzled
  __shared__ float Mmax[2][128];
  __shared__ float KsumS[64];

  int bx = blockIdx.x;            // 0..31
  int b = blockIdx.y;
  int qt = bx >> 1, h = bx & 1;
  int q0 = qt * 128;
  int t = threadIdx.x;
  int w = t >> 6, L = t & 63;

  if (h == 0 && t < 64) {
    float s = 0.f;
#pragma unroll
    for (int p = 0; p < 16; ++p) s += Kpart[(b * 16 + p) * 64 + t];
    KsumS[t] = s;
  }

  // stage Q tile once: read fp32, convert to bf16, swizzled store
  int g = t & 7;
  int rbase = t >> 3;
  {
#pragma unroll
    for (int it = 0; it < 4; ++it) {
      int r = it * 32 + rbase;
      const float* src = Q + ((size_t)b * LL + q0 + r) * DD + g * 8;
      float4 a = *(const float4*)src;
      float4 c4 = *(const float4*)(src + 4);
      *(int4*)&Qs[r * 64 + 8 * (g ^ (r & 7))] = pack_bf16x8(a, c4);
    }
  }

  f32x4 mx[4];
#pragma unroll
  for (int i = 0; i < 4; ++i) mx[i] = (f32x4){NEG_BIG, NEG_BIG, NEG_BIG, NEG_BIG};

  const int waveQ = 64 * (w & 1);
  const int waveK = 64 * (w >> 1);
  const int lm = L & 15;
  const int lq = L >> 4;

  const ushort_t* KgH = Kg + ((size_t)b * LL + h * 1024) * DD;

  // prefetch chunk 0
  int4 pre[4];
#pragma unroll
  for (int it = 0; it < 4; ++it)
    pre[it] = *(const int4*)(KgH + (size_t)(it * 32 + rbase) * DD + g * 8);

  for (int c = 0; c < 8; ++c) {
    __syncthreads();  // previous chunk's LDS readers done
    // write prefetched chunk to LDS (swizzled)
#pragma unroll
    for (int it = 0; it < 4; ++it) {
      int r = it * 32 + rbase;
      *(int4*)&Ks[r * 64 + 8 * (g ^ (r & 7))] = pre[it];
    }
    __syncthreads();
    // issue next chunk's loads BEFORE the MFMA section -> latency overlaps
    if (c < 7) {
#pragma unroll
      for (int it = 0; it < 4; ++it)
        pre[it] = *(const int4*)(KgH + (size_t)((c + 1) * 128 + it * 32 + rbase) * DD + g * 8);
    }

    f32x4 acc[4][4];
#pragma unroll
    for (int i = 0; i < 4; ++i)
#pragma unroll
      for (int j = 0; j < 4; ++j) acc[i][j] = (f32x4){0.f, 0.f, 0.f, 0.f};

#pragma unroll
    for (int s = 0; s < 2; ++s) {
      int gg = 4 * s + lq;
      short8 A[4];
#pragma unroll
      for (int qt2 = 0; qt2 < 4; ++qt2) {
        int r = waveQ + 16 * qt2 + lm;
        A[qt2] = *(const short8*)&Qs[r * 64 + 8 * (gg ^ (r & 7))];
      }
#pragma unroll
      for (int kt = 0; kt < 4; ++kt) {
        int rB = waveK + 16 * kt + lm;
        short8 Bf = *(const short8*)&Ks[rB * 64 + 8 * (gg ^ (rB & 7))];
#pragma unroll
        for (int qt2 = 0; qt2 < 4; ++qt2) {
          acc[qt2][kt] = __builtin_amdgcn_mfma_f32_16x16x32_bf16(A[qt2], Bf, acc[qt2][kt], 0, 0, 0);
        }
      }
    }
#pragma unroll
    for (int qt2 = 0; qt2 < 4; ++qt2)
#pragma unroll
      for (int kt = 0; kt < 4; ++kt) {
#pragma unroll
        for (int r4 = 0; r4 < 4; ++r4) mx[qt2][r4] = fmaxf(mx[qt2][r4], acc[qt2][kt][r4]);
      }
  }

#pragma unroll
  for (int qt2 = 0; qt2 < 4; ++qt2) {
#pragma unroll
    for (int r4 = 0; r4 < 4; ++r4) {
      float v = mx[qt2][r4];
      v = fmaxf(v, __shfl_xor(v, 1));
      v = fmaxf(v, __shfl_xor(v, 2));
      v = fmaxf(v, __shfl_xor(v, 4));
      v = fmaxf(v, __shfl_xor(v, 8));
      mx[qt2][r4] = v;
    }
  }
  if (lm < 4) {
    int qt2 = lm;
#pragma unroll
    for (int r4 = 0; r4 < 4; ++r4) {
      Mmax[w >> 1][waveQ + 16 * qt2 + 4 * lq + r4] = mx[qt2][r4];
    }
  }
  __syncthreads();

  if (t < 128) {
    float m = fmaxf(Mmax[0][t], Mmax[1][t]);
    Mhalf[((size_t)b * 2 + h) * LL + q0 + t] = m;
    if (h == 0) {
      const float4* Qr = (const float4*)(Q + ((size_t)b * LL + q0 + t) * DD);
      float s = 0.f;
#pragma unroll
      for (int i = 0; i < 16; ++i) {
        float4 qv = Qr[i];
        s += qv.x * KsumS[4 * i] + qv.y * KsumS[4 * i + 1] + qv.z * KsumS[4 * i + 2] +
             qv.w * KsumS[4 * i + 3];
      }
      Mmean[b * LL + q0 + t] = s * (1.0f / (float)LL);
    }
  }
}

// ---------------------------------------------------------------------------
// Kernel 3: per-batch top-64 candidate set (set only; any order).
// M[q] = max(Mhalf[0][q], Mhalf[1][q]) - Mmean[q]  (bit-identical to r7 Mb).
// ---------------------------------------------------------------------------
__global__ __launch_bounds__(256) void cand_kernel(const float* __restrict__ Mhalf,
                                                   const float* __restrict__ Mmean,
                                                   int* __restrict__ cand) {
  int b = blockIdx.x, t = threadIdx.x;
  int w = t >> 6;
  float v[8];
#pragma unroll
  for (int i = 0; i < 8; ++i) {
    int q = t + 256 * i;
    float m = fmaxf(Mhalf[((size_t)b * 2) * LL + q], Mhalf[((size_t)b * 2 + 1) * LL + q]);
    v[i] = m - Mmean[b * LL + q];
  }
  __shared__ ull warr[4];
  __shared__ ull winls;
  for (int round = 0; round < CC; ++round) {
    float bv = v[0];
    int bi = 0;
#pragma unroll
    for (int i = 1; i < 8; ++i)
      if (v[i] > bv) { bv = v[i]; bi = i; }
    ull key = ((ull)fsort(bv) << 32) | (ull)(uint)(t + 256 * bi);
#pragma unroll
    for (int m = 1; m < 64; m <<= 1) {
      ull o = shfl_xor_u64(key, m);
      if (o > key) key = o;
    }
    if ((t & 63) == 0) warr[w] = key;
    __syncthreads();
    if (t == 0) {
      ull k = warr[0];
#pragma unroll
      for (int i = 1; i < 4; ++i)
        if (warr[i] > k) k = warr[i];
      winls = k;
      cand[b * CC + round] = (int)(k & 0xFFFFFFFFull);
    }
    __syncthreads();
    int wj = (int)(winls & 0xFFFFFFFFull);
    if (t == (wj & 255)) v[wj >> 8] = NEG_BIG;
  }
}

// ---------------------------------------------------------------------------
// Kernel 4: fp32 rescue partial maxes — register-tiled GEMM-max.
// ---------------------------------------------------------------------------
__global__ __launch_bounds__(256) void rescue_kernel(const float* __restrict__ Q,
                                                     const float* __restrict__ K,
                                                     const int* __restrict__ idx,
                                                     const int* __restrict__ cand,
                                                     float* __restrict__ Mpart) {
  __shared__ float Qc[64][68];    // 17408 B
  __shared__ float Kt[128][68];   // 34816 B
  __shared__ float red[64][33];   // 8448 B
  __shared__ int cidx[CC];
  int seg = blockIdx.x, b = blockIdx.y, t = threadIdx.x;

  if (t < CC) cidx[t] = cand[b * CC + t];
  __syncthreads();
  for (int li = t; li < 64 * 16; li += 256) {
    int row = li >> 4, g4 = li & 15;
    *(float4*)&Qc[row][4 * g4] =
        *(const float4*)(Q + ((size_t)b * LL + cidx[row]) * DD + 4 * g4);
  }
  for (int li = t; li < 128 * 16; li += 256) {
    int row = li >> 4, g4 = li & 15;
    int gk = idx[seg * 128 + row];
    *(float4*)&Kt[row][4 * g4] =
        *(const float4*)(K + ((size_t)b * LL + gk) * DD + 4 * g4);
  }
  __syncthreads();

  int tx = t & 7;
  int ty = t >> 3;
  float acc[8][4];
#pragma unroll
  for (int i = 0; i < 8; ++i)
#pragma unroll
    for (int j = 0; j < 4; ++j) acc[i][j] = 0.f;

#pragma unroll 4
  for (int dd = 0; dd < 64; dd += 4) {
    float4 qf[8];
#pragma unroll
    for (int i = 0; i < 8; ++i) qf[i] = *(const float4*)&Qc[tx + 8 * i][dd];
    float4 kf[4];
#pragma unroll
    for (int j = 0; j < 4; ++j) kf[j] = *(const float4*)&Kt[ty + 32 * j][dd];
#pragma unroll
    for (int i = 0; i < 8; ++i)
#pragma unroll
      for (int j = 0; j < 4; ++j) {
        float d = acc[i][j];
        d = fmaf(qf[i].x, kf[j].x, d);
        d = fmaf(qf[i].y, kf[j].y, d);
        d = fmaf(qf[i].z, kf[j].z, d);
        d = fmaf(qf[i].w, kf[j].w, d);
        acc[i][j] = d;
      }
  }

#pragma unroll
  for (int i = 0; i < 8; ++i) {
    float m = fmaxf(fmaxf(acc[i][0], acc[i][1]), fmaxf(acc[i][2], acc[i][3]));
    red[tx + 8 * i][ty] = m;
  }
  __syncthreads();
  if (t < CC) {
    float m = red[t][0];
#pragma unroll
    for (int tt = 1; tt < 32; ++tt) m = fmaxf(m, red[t][tt]);
    Mpart[((size_t)b * CC + t) * FSEG + seg] = m;
  }
}

// ---------------------------------------------------------------------------
// Kernel 5: exact fp32 M for candidates; top-40 via rank-by-counting.
// ---------------------------------------------------------------------------
__global__ __launch_bounds__(64) void select_kernel(const float* __restrict__ Q,
                                                    const float* __restrict__ Kpart,
                                                    const int* __restrict__ cand,
                                                    const float* __restrict__ Mpart,
                                                    int* __restrict__ topi) {
  int b = blockIdx.x, t = threadIdx.x;
  __shared__ float KsumS[64];
  __shared__ ull keys[CC];
  {
    float s = 0.f;
#pragma unroll
    for (int p = 0; p < 16; ++p) s += Kpart[(b * 16 + p) * 64 + t];
    KsumS[t] = s;
  }
  __syncthreads();
  int ci = cand[b * CC + t];
  float m = NEG_BIG;
#pragma unroll
  for (int s = 0; s < FSEG; ++s) m = fmaxf(m, Mpart[((size_t)b * CC + t) * FSEG + s]);
  const float4* Qr = (const float4*)(Q + ((size_t)b * LL + ci) * DD);
  float s = 0.f;
#pragma unroll
  for (int i = 0; i < 16; ++i) {
    float4 qv = Qr[i];
    s += qv.x * KsumS[4 * i] + qv.y * KsumS[4 * i + 1] + qv.z * KsumS[4 * i + 2] +
         qv.w * KsumS[4 * i + 3];
  }
  float Mf = m - s * (1.0f / (float)LL);
  ull key = ((ull)fsort(Mf) << 32) | (ull)(uint)(2047 - ci);
  keys[t] = key;
  __syncthreads();
  int rank = 0;
#pragma unroll 8
  for (int j = 0; j < CC; ++j) rank += (keys[j] > key) ? 1 : 0;
  if (rank < UU) topi[b * UU + rank] = ci;
}

// ---------------------------------------------------------------------------
// Kernel 6: FUSED epilogue per (seg, b), 128 keys/seg.
// ---------------------------------------------------------------------------
__global__ __launch_bounds__(256, 2) void fused_epilogue_kernel(
    const float* __restrict__ Q, const float* __restrict__ K,
    const float* __restrict__ V, const int* __restrict__ topi,
    float* __restrict__ scores, float* __restrict__ Opart,
    float* __restrict__ lpart) {
  int seg = blockIdx.x, b = blockIdx.y, t = threadIdx.x;
  __shared__ int cidx[UU];
  __shared__ float Qc[UU][DD];       // 10240 B
  __shared__ float pT[128 * PSTR];   // 21504 B; aliased as red[2][40][64]
  __shared__ float lw[4][20];        // 320 B

  if (t < UU) cidx[t] = topi[b * UU + t];
  __syncthreads();
  for (int li = t; li < UU * 16; li += 256) {
    int u = li >> 4, g4 = li & 15;
    *(float4*)&Qc[u][4 * g4] =
        *(const float4*)(Q + ((size_t)b * LL + cidx[u]) * DD + 4 * g4);
  }
  __syncthreads();

  int kl = t & 127, uh = t >> 7, w = t >> 6;
  int k = seg * 128 + kl;
  float4 kr[16];
  const float4* Krow = (const float4*)(K + ((size_t)b * LL + k) * DD);
#pragma unroll
  for (int i = 0; i < 16; ++i) kr[i] = Krow[i];

  float p[20];
#pragma unroll 4
  for (int j = 0; j < 20; ++j) {
    int u = uh * 20 + j;
    const float4* qp = (const float4*)&Qc[u][0];
    float s = 0.f;
#pragma unroll
    for (int i = 0; i < 16; ++i) {
      float4 qv = qp[i];  // broadcast LDS read
      s += qv.x * kr[i].x + qv.y * kr[i].y + qv.z * kr[i].z + qv.w * kr[i].w;
    }
    s *= 0.125f;
    scores[((size_t)(b * UU + u)) * LL + k] = s;
    p[j] = __expf(s);
  }

#pragma unroll
  for (int j = 0; j < 20; ++j) {
    float ls = p[j];
#pragma unroll
    for (int off = 32; off > 0; off >>= 1) ls += __shfl_xor(ls, off);
    if ((t & 63) == 0) lw[w][j] = ls;
  }
#pragma unroll
  for (int j = 0; j < 20; j += 2) {
    *(float2*)&pT[kl * PSTR + uh * 20 + j] = make_float2(p[j], p[j + 1]);
  }
  __syncthreads();
  if (t < UU) {
    int u = t;
    float ls = (u < 20) ? (lw[0][u] + lw[1][u]) : (lw[2][u - 20] + lw[3][u - 20]);
    lpart[(size_t)(b * FSEG + seg) * UU + u] = ls;
  }

  int d4 = t & 15, c = t >> 4;
  int ug = c & 7, kq = c >> 3;
  int u0 = ug * 5;
  float4 acc[5];
#pragma unroll
  for (int j = 0; j < 5; ++j) acc[j] = (float4){0.f, 0.f, 0.f, 0.f};
  const float* Vb = V + ((size_t)b * LL + seg * 128 + kq * 64) * DD;
  for (int kk = 0; kk < 64; ++kk) {
    float4 v4 = *(const float4*)(Vb + (size_t)kk * DD + 4 * d4);
    const float* prow = &pT[(kq * 64 + kk) * PSTR + u0];
#pragma unroll
    for (int j = 0; j < 5; ++j) {
      float pj = prow[j];
      acc[j].x += pj * v4.x; acc[j].y += pj * v4.y;
      acc[j].z += pj * v4.z; acc[j].w += pj * v4.w;
    }
  }
  __syncthreads();
  float* red = pT;
#pragma unroll
  for (int j = 0; j < 5; ++j)
    *(float4*)&red[(kq * 40 + u0 + j) * 64 + 4 * d4] = acc[j];
  __syncthreads();
  for (int li = t; li < UU * DD; li += 256) {
    int u = li >> 6, d = li & 63;
    float s = red[u * 64 + d] + red[(40 + u) * 64 + d];
    Opart[((size_t)(b * FSEG + seg) * UU + u) * DD + d] = s;
  }
}

// ---------------------------------------------------------------------------
// Kernel 7: combine segments: out = (sum_s Opart) / (sum_s lpart).
// ---------------------------------------------------------------------------
__global__ __launch_bounds__(256) void combine_kernel(const float* __restrict__ Opart,
                                                      const float* __restrict__ lpart,
                                                      float* __restrict__ out) {
  int b = blockIdx.x, t = threadIdx.x;
  __shared__ float Linv[UU];
  if (t < UU) {
    float Lsum = 0.f;
#pragma unroll
    for (int s = 0; s < FSEG; ++s) Lsum += lpart[(size_t)(b * FSEG + s) * UU + t];
    Linv[t] = 1.0f / Lsum;
  }
  __syncthreads();
  for (int li = t; li < UU * DD; li += 256) {
    int u = li >> 6, d = li & 63;
    float O = 0.f;
#pragma unroll
    for (int s = 0; s < FSEG; ++s)
      O += Opart[((size_t)(b * FSEG + s) * UU + u) * DD + d];
    out[((size_t)b * UU + u) * DD + d] = O * Linv[u];
  }
}

// ========================= fp32 fallback (round-2 path) ====================
__global__ __launch_bounds__(256) void ksum_kernel(const float* __restrict__ K,
                                                   const int* __restrict__ idx,
                                                   float* __restrict__ Kpart) {
  int p = blockIdx.x, b = blockIdx.y, tid = threadIdx.x;
  int d = tid & 63, c = tid >> 6;
  const float* Kb = K + (size_t)b * LL * DD;
  float acc = 0.f;
  int j0 = p * 128 + c * 32;
#pragma unroll 4
  for (int t = 0; t < 32; ++t) acc += Kb[(size_t)idx[j0 + t] * DD + d];
  __shared__ float red[256];
  red[tid] = acc;
  __syncthreads();
  if (c == 0) Kpart[(b * 16 + p) * 64 + d] = red[d] + red[64 + d] + red[128 + d] + red[192 + d];
}

__global__ __launch_bounds__(256) void m_kernel(const float* __restrict__ Q,
                                                const float* __restrict__ K,
                                                const int* __restrict__ idx,
                                                const float* __restrict__ Kpart,
                                                float* __restrict__ M) {
  __shared__ float Qs[128][68];
  __shared__ float Ks[128][68];
  __shared__ float KsumS[64];
  __shared__ float red[128][17];
  int b = blockIdx.y, q0 = blockIdx.x * 128, tid = threadIdx.x;
  int tx = tid & 15, ty = tid >> 4;
  if (tid < 64) {
    float s = 0.f;
#pragma unroll
    for (int p = 0; p < 16; ++p) s += Kpart[(b * 16 + p) * 64 + tid];
    KsumS[tid] = s;
  }
#pragma unroll
  for (int it = 0; it < 8; ++it) {
    int li = it * 256 + tid;
    int q = li >> 4, dd = (li & 15) << 2;
    *(float4*)&Qs[q][dd] = *(const float4*)(Q + ((size_t)b * LL + q0 + q) * DD + dd);
  }
  float mx[8];
#pragma unroll
  for (int i = 0; i < 8; ++i) mx[i] = NEG_BIG;
  for (int c = 0; c < LL / 128; ++c) {
    __syncthreads();
#pragma unroll
    for (int it = 0; it < 8; ++it) {
      int li = it * 256 + tid;
      int kk = li >> 4, dd = (li & 15) << 2;
      int gk = idx[c * 128 + kk];
      *(float4*)&Ks[kk][dd] = *(const float4*)(K + ((size_t)b * LL + gk) * DD + dd);
    }
    __syncthreads();
    float acc[8][8];
#pragma unroll
    for (int i = 0; i < 8; ++i)
#pragma unroll
      for (int j = 0; j < 8; ++j) acc[i][j] = 0.f;
#pragma unroll 2
    for (int dd = 0; dd < 64; dd += 4) {
      float4 qf[8];
#pragma unroll
      for (int i = 0; i < 8; ++i) qf[i] = *(const float4*)&Qs[tx + 16 * i][dd];
#pragma unroll
      for (int j = 0; j < 8; ++j) {
        float4 kf = *(const float4*)&Ks[ty + 16 * j][dd];
#pragma unroll
        for (int i = 0; i < 8; ++i)
          acc[i][j] += qf[i].x * kf.x + qf[i].y * kf.y + qf[i].z * kf.z + qf[i].w * kf.w;
      }
    }
#pragma unroll
    for (int i = 0; i < 8; ++i) {
      float m01 = fmaxf(fmaxf(acc[i][0], acc[i][1]), fmaxf(acc[i][2], acc[i][3]));
      float m23 = fmaxf(fmaxf(acc[i][4], acc[i][5]), fmaxf(acc[i][6], acc[i][7]));
      mx[i] = fmaxf(mx[i], fmaxf(m01, m23));
    }
  }
  __syncthreads();
#pragma unroll
  for (int i = 0; i < 8; ++i) red[tx + 16 * i][ty] = mx[i];
  __syncthreads();
  if (tid < 128) {
    float m = red[tid][0];
#pragma unroll
    for (int tt = 1; tt < 16; ++tt) m = fmaxf(m, red[tid][tt]);
    float s = 0.f;
#pragma unroll 16
    for (int d = 0; d < 64; ++d) s += Qs[tid][d] * KsumS[d];
    M[b * LL + q0 + tid] = m - s * (1.0f / (float)LL);
  }
}

__global__ __launch_bounds__(256) void topk_kernel(const float* __restrict__ M,
                                                   int* __restrict__ topi) {
  int b = blockIdx.x, tid = threadIdx.x;
  __shared__ float mv[LL];
  __shared__ float wv[4];
  __shared__ int wi[4];
  for (int j = tid; j < LL; j += 256) mv[j] = M[b * LL + j];
  __syncthreads();
  for (int t = 0; t < UU; ++t) {
    float bv = NEG_BIG;
    int bi = 0x7fffffff;
    for (int j = tid; j < LL; j += 256) {
      float v = mv[j];
      if (v > bv) { bv = v; bi = j; }
    }
#pragma unroll
    for (int off = 32; off > 0; off >>= 1) {
      float ov = __shfl_down(bv, off);
      int oi = __shfl_down(bi, off);
      if (ov > bv || (ov == bv && oi < bi)) { bv = ov; bi = oi; }
    }
    if ((tid & 63) == 0) { wv[tid >> 6] = bv; wi[tid >> 6] = bi; }
    __syncthreads();
    if (tid == 0) {
#pragma unroll
      for (int w = 1; w < 4; ++w)
        if (wv[w] > bv || (wv[w] == bv && wi[w] < bi)) { bv = wv[w]; bi = wi[w]; }
      topi[b * UU + t] = bi;
      mv[bi] = NEG_BIG;
    }
    __syncthreads();
  }
}

__global__ __launch_bounds__(256) void scores_kernel(const float* __restrict__ Q,
                                                     const float* __restrict__ K,
                                                     const int* __restrict__ topi,
                                                     float* __restrict__ scores) {
  int b = blockIdx.y;
  int k = blockIdx.x * 256 + threadIdx.x;
  __shared__ float Qr[UU][DD];
  for (int li = threadIdx.x; li < UU * DD; li += 256) {
    int u = li >> 6, d = li & 63;
    Qr[u][d] = Q[((size_t)b * LL + topi[b * UU + u]) * DD + d];
  }
  __syncthreads();
  float4 kr[16];
  const float4* Krow = (const float4*)(K + ((size_t)b * LL + k) * DD);
#pragma unroll
  for (int i = 0; i < 16; ++i) kr[i] = Krow[i];
  for (int u = 0; u < UU; ++u) {
    float s = 0.f;
#pragma unroll
    for (int i = 0; i < 16; ++i) {
      float4 qv = *(const float4*)&Qr[u][i << 2];
      s += qv.x * kr[i].x + qv.y * kr[i].y + qv.z * kr[i].z + qv.w * kr[i].w;
    }
    scores[((size_t)(b * UU + u)) * LL + k] = s * 0.125f;
  }
}

__global__ __launch_bounds__(256) void softmax_pv_kernel(const float* __restrict__ scores,
                                                         const float* __restrict__ V,
                                                         float* __restrict__ out) {
  int b = blockIdx.y;
  int u0 = blockIdx.x * 4;
  int tid = threadIdx.x;
  __shared__ float p[4][LL];
  __shared__ float wred[4];
  __shared__ float inv_s[4];
  __shared__ float r2[256];
#pragma unroll
  for (int uu = 0; uu < 4; ++uu) {
    const float* srow = scores + ((size_t)(b * UU + u0 + uu)) * LL;
    float m = NEG_BIG;
    for (int j = tid; j < LL; j += 256) m = fmaxf(m, srow[j]);
#pragma unroll
    for (int off = 32; off > 0; off >>= 1) m = fmaxf(m, __shfl_down(m, off));
    if ((tid & 63) == 0) wred[tid >> 6] = m;
    __syncthreads();
    float smax = fmaxf(fmaxf(wred[0], wred[1]), fmaxf(wred[2], wred[3]));
    __syncthreads();
    float ls = 0.f;
    for (int j = tid; j < LL; j += 256) {
      float e = __expf(srow[j] - smax);
      p[uu][j] = e;
      ls += e;
    }
#pragma unroll
    for (int off = 32; off > 0; off >>= 1) ls += __shfl_down(ls, off);
    if ((tid & 63) == 0) wred[tid >> 6] = ls;
    __syncthreads();
    if (tid == 0) inv_s[uu] = 1.0f / (wred[0] + wred[1] + wred[2] + wred[3]);
    __syncthreads();
  }
  int d = tid & 63, c = tid >> 6;
  float acc[4] = {0.f, 0.f, 0.f, 0.f};
  const float* Vb = V + (size_t)b * LL * DD;
  int k0 = c * (LL / 4), k1 = k0 + (LL / 4);
  for (int k = k0; k < k1; ++k) {
    float v = Vb[(size_t)k * DD + d];
#pragma unroll
    for (int uu = 0; uu < 4; ++uu) acc[uu] += p[uu][k] * v;
  }
#pragma unroll
  for (int uu = 0; uu < 4; ++uu) {
    r2[tid] = acc[uu];
    __syncthreads();
    if (c == 0) {
      out[((size_t)(b * UU) + u0 + uu) * DD + d] =
          (r2[d] + r2[64 + d] + r2[128 + d] + r2[192 + d]) * inv_s[uu];
    }
    __syncthreads();
  }
}

// ---------------------------------------------------------------------------
extern "C" void kernel_launch(void* const* d_in, const int* in_sizes, int n_in,
                              void* d_out, int out_size, void* d_ws, size_t ws_size,
                              hipStream_t stream) {
  (void)in_sizes; (void)n_in; (void)out_size;
  const float* Q = (const float*)d_in[0];
  const float* K = (const float*)d_in[1];
  const float* V = (const float*)d_in[2];
  const int* idx = (const int*)d_in[3];

  float* out = (float*)d_out;
  float* scores = out + (size_t)BB * UU * DD;

  // fast-path workspace layout (~9.4 MB)
  const size_t kg_off = 0;  // Kg bf16: 8 MB; Opart/lpart alias it after mfma_m
  const size_t kpart_off = kg_off + (size_t)BB * LL * DD * sizeof(ushort_t);
  const size_t mhalf_off = kpart_off + (size_t)BB * 16 * DD * sizeof(float);
  const size_t mmean_off = mhalf_off + (size_t)BB * 2 * LL * sizeof(float);
  const size_t mpart_off = mmean_off + (size_t)BB * LL * sizeof(float);
  const size_t cand_off = mpart_off + (size_t)BB * CC * FSEG * sizeof(float);
  const size_t topi_off = cand_off + (size_t)BB * CC * sizeof(int);
  const size_t need = topi_off + (size_t)BB * UU * sizeof(int);

  char* ws = (char*)d_ws;
  if (ws_size >= need) {
    ushort_t* Kg = (ushort_t*)(ws + kg_off);
    float* Kpart = (float*)(ws + kpart_off);
    float* Mhalf = (float*)(ws + mhalf_off);
    float* Mmean = (float*)(ws + mmean_off);
    float* Mpart = (float*)(ws + mpart_off);
    int* cand = (int*)(ws + cand_off);
    int* topi = (int*)(ws + topi_off);
    // Opart (5.24 MB) + lpart alias the Kg region (dead after mfma_m).
    float* Opart = (float*)(ws + kg_off);
    float* lpart = Opart + (size_t)BB * FSEG * UU * DD;

    prep_ksum_kernel<<<dim3(16, BB), 256, 0, stream>>>(K, idx, Kg, Kpart);
    mfma_m_kernel<<<dim3(32, BB), 256, 0, stream>>>(Q, Kg, Kpart, Mhalf, Mmean);
    cand_kernel<<<BB, 256, 0, stream>>>(Mhalf, Mmean, cand);
    rescue_kernel<<<dim3(FSEG, BB), 256, 0, stream>>>(Q, K, idx, cand, Mpart);
    select_kernel<<<BB, 64, 0, stream>>>(Q, Kpart, cand, Mpart, topi);
    fused_epilogue_kernel<<<dim3(FSEG, BB), 256, 0, stream>>>(Q, K, V, topi, scores,
                                                              Opart, lpart);
    combine_kernel<<<BB, 256, 0, stream>>>(Opart, lpart, out);
  } else {
    // fp32 fallback (round-2 path), aliasing dead d_out regions
    size_t need2 =
        (size_t)(BB * LL + BB * 16 * DD) * sizeof(float) + (size_t)(BB * UU) * sizeof(int);
    float* M;
    float* Kpart;
    int* topi;
    if (ws_size >= need2) {
      M = (float*)d_ws;
      Kpart = M + BB * LL;
      topi = (int*)(Kpart + BB * 16 * DD);
    } else {
      M = scores;
      Kpart = scores + BB * LL;
      topi = (int*)out;
    }
    ksum_kernel<<<dim3(16, BB), 256, 0, stream>>>(K, idx, Kpart);
    m_kernel<<<dim3(LL / 128, BB), 256, 0, stream>>>(Q, K, idx, Kpart, M);
    topk_kernel<<<BB, 256, 0, stream>>>(M, topi);
    scores_kernel<<<dim3(LL / 256, BB), 256, 0, stream>>>(Q, K, topi, scores);
    softmax_pv_kernel<<<dim3(UU / 4, BB), 256, 0, stream>>>(scores, V, out);
  }
}

// Round 9
// 203.859 us; speedup vs baseline: 1.2066x; 1.2066x over previous
//
#include <hip/hip_runtime.h>
#include <math.h>

#define BB 32
#define LL 2048
#define DD 64
#define UU 40
#define CC 64            // bf16-phase candidates per batch
#define FSEG 16          // epilogue/rescue key segments (128 keys each)
#define PSTR 42          // pT row stride (floats); even -> 8B-aligned b64 ops
#define NEG_BIG (-3.0e38f)

typedef __attribute__((ext_vector_type(8))) short short8;
typedef __attribute__((ext_vector_type(4))) float f32x4;
typedef unsigned long long ull;
typedef unsigned int uint;
typedef unsigned short ushort_t;

__device__ __forceinline__ unsigned short f2bf(float f) {
  uint u = __float_as_uint(f);
  u += 0x7FFFu + ((u >> 16) & 1u);   // RNE
  return (unsigned short)(u >> 16);
}
__device__ __forceinline__ uint fsort(float f) {
  uint u = __float_as_uint(f);
  return (u & 0x80000000u) ? ~u : (u | 0x80000000u);  // monotonic map
}
__device__ __forceinline__ ull shfl_xor_u64(ull x, int m) {
  uint lo = (uint)x, hi = (uint)(x >> 32);
  lo = __shfl_xor(lo, m);
  hi = __shfl_xor(hi, m);
  return ((ull)hi << 32) | lo;
}
__device__ __forceinline__ int4 pack_bf16x8(float4 a, float4 c4) {
  int4 o;
  o.x = (int)(f2bf(a.x) | ((uint)f2bf(a.y) << 16));
  o.y = (int)(f2bf(a.z) | ((uint)f2bf(a.w) << 16));
  o.z = (int)(f2bf(c4.x) | ((uint)f2bf(c4.y) << 16));
  o.w = (int)(f2bf(c4.z) | ((uint)f2bf(c4.w) << 16));
  return o;
}
// async 16B/lane global->LDS copy (gfx950). LDS dest = uniform base + lane*16.
__device__ __forceinline__ void async_copy16(const void* g, void* l) {
  __builtin_amdgcn_global_load_lds((const __attribute__((address_space(1))) void*)g,
                                   (__attribute__((address_space(3))) void*)l, 16, 0, 0);
}

// ---------------------------------------------------------------------------
// Kernel 1: gathered K -> bf16 Kg (PRE-SWIZZLED rows: 16B group g stored at
// slot g^(r&7); byte permutation within each 128B row, coalescing kept) +
// partial Ksum (Kpart) in one pass.
// ---------------------------------------------------------------------------
__global__ __launch_bounds__(256) void prep_ksum_kernel(const float* __restrict__ K,
                                                        const int* __restrict__ idx,
                                                        ushort_t* __restrict__ Kg,
                                                        float* __restrict__ Kpart) {
  int p = blockIdx.x, b = blockIdx.y, t = threadIdx.x;
  int g = t & 7;  // 16B group = 8 elements
  float4 sa = {0.f, 0.f, 0.f, 0.f}, sb = {0.f, 0.f, 0.f, 0.f};
#pragma unroll
  for (int it = 0; it < 4; ++it) {
    int r = p * 128 + it * 32 + (t >> 3);
    int gk = idx[r];
    const float* src = K + ((size_t)b * LL + gk) * DD + g * 8;
    float4 a = *(const float4*)src;
    float4 c4 = *(const float4*)(src + 4);
    sa.x += a.x; sa.y += a.y; sa.z += a.z; sa.w += a.w;
    sb.x += c4.x; sb.y += c4.y; sb.z += c4.z; sb.w += c4.w;
    *(int4*)(Kg + ((size_t)b * LL + r) * DD + 8 * (g ^ (r & 7))) = pack_bf16x8(a, c4);
  }
  __shared__ float red[32][64];
  int rt = t >> 3;
  *(float4*)&red[rt][g * 8] = sa;
  *(float4*)&red[rt][g * 8 + 4] = sb;
  __syncthreads();
  if (t < 64) {
    float s = 0.f;
#pragma unroll
    for (int r = 0; r < 32; ++r) s += red[r][t];
    Kpart[(b * 16 + p) * 64 + t] = s;
  }
}

// ---------------------------------------------------------------------------
// Kernel 2: bf16 MFMA M-scores (r7 base + async double-buffered K staging).
// Chunk c+1 is DMA'd into the other Ks buffer via global_load_lds while the
// MFMA section runs on chunk c; the barrier's vmcnt drain lands after the
// MFMA section instead of before it. Kg arrives pre-swizzled so the identity
// lane->LDS mapping of global_load_lds reproduces the swizzled image.
// Mb[b][q] = max_j(Q.K_sample[j]) - (Q.Ksum)/L.  (bit-identical to r7)
// ---------------------------------------------------------------------------
__global__ __launch_bounds__(256) void mfma_m_kernel(const float* __restrict__ Q,
                                                     const ushort_t* __restrict__ Kg,
                                                     const float* __restrict__ Kpart,
                                                     float* __restrict__ Mb) {
  __shared__ __align__(16) ushort_t Qs[128 * 64];      // 16 KB, swizzled
  __shared__ __align__(16) ushort_t Ks[2][128 * 64];   // 2 x 16 KB, swizzled
  __shared__ float Mmax[2][128];
  __shared__ float KsumS[64];

  int b = blockIdx.y, q0 = blockIdx.x * 128;
  int t = threadIdx.x;
  int w = t >> 6, L = t & 63;

  const ushort_t* KgB = Kg + (size_t)b * LL * DD;

  // issue chunk 0 async into Ks[0] (flies during Ksum + Q staging)
#pragma unroll
  for (int i = 0; i < 4; ++i) {
    const ushort_t* gp =
        KgB + (size_t)(w * 32 + i * 8 + (L >> 3)) * DD + (L & 7) * 8;
    async_copy16(gp, &Ks[0][(w * 32 + i * 8) * 64]);
  }

  if (t < 64) {
    float s = 0.f;
#pragma unroll
    for (int p = 0; p < 16; ++p) s += Kpart[(b * 16 + p) * 64 + t];
    KsumS[t] = s;
  }

  // stage Q tile once: read fp32, convert to bf16, swizzled store
  {
    int g = t & 7;
#pragma unroll
    for (int it = 0; it < 4; ++it) {
      int r = it * 32 + (t >> 3);
      const float* src = Q + ((size_t)b * LL + q0 + r) * DD + g * 8;
      float4 a = *(const float4*)src;
      float4 c4 = *(const float4*)(src + 4);
      *(int4*)&Qs[r * 64 + 8 * (g ^ (r & 7))] = pack_bf16x8(a, c4);
    }
  }
  __syncthreads();  // drains chunk-0 DMA + Q staging

  f32x4 mx[4];
#pragma unroll
  for (int i = 0; i < 4; ++i) mx[i] = (f32x4){NEG_BIG, NEG_BIG, NEG_BIG, NEG_BIG};

  const int waveQ = 64 * (w & 1);
  const int waveK = 64 * (w >> 1);
  const int lm = L & 15;
  const int lq = L >> 4;

  for (int c = 0; c < LL / 128; ++c) {
    int cur = c & 1;
    // issue next chunk's DMA before the MFMA section (overlap)
    if (c < LL / 128 - 1) {
      int nxt = cur ^ 1;
#pragma unroll
      for (int i = 0; i < 4; ++i) {
        const ushort_t* gp =
            KgB + (size_t)((c + 1) * 128 + w * 32 + i * 8 + (L >> 3)) * DD + (L & 7) * 8;
        async_copy16(gp, &Ks[nxt][(w * 32 + i * 8) * 64]);
      }
    }

    f32x4 acc[4][4];
#pragma unroll
    for (int i = 0; i < 4; ++i)
#pragma unroll
      for (int j = 0; j < 4; ++j) acc[i][j] = (f32x4){0.f, 0.f, 0.f, 0.f};

#pragma unroll
    for (int s = 0; s < 2; ++s) {
      int g = 4 * s + lq;
      short8 A[4];
#pragma unroll
      for (int qt = 0; qt < 4; ++qt) {
        int r = waveQ + 16 * qt + lm;
        A[qt] = *(const short8*)&Qs[r * 64 + 8 * (g ^ (r & 7))];
      }
#pragma unroll
      for (int kt = 0; kt < 4; ++kt) {
        int rB = waveK + 16 * kt + lm;
        short8 Bf = *(const short8*)&Ks[cur][rB * 64 + 8 * (g ^ (rB & 7))];
#pragma unroll
        for (int qt = 0; qt < 4; ++qt) {
          acc[qt][kt] = __builtin_amdgcn_mfma_f32_16x16x32_bf16(A[qt], Bf, acc[qt][kt], 0, 0, 0);
        }
      }
    }
#pragma unroll
    for (int qt = 0; qt < 4; ++qt)
#pragma unroll
      for (int kt = 0; kt < 4; ++kt) {
#pragma unroll
        for (int r4 = 0; r4 < 4; ++r4) mx[qt][r4] = fmaxf(mx[qt][r4], acc[qt][kt][r4]);
      }
    __syncthreads();  // drains next-chunk DMA; protects cur buf for overwrite
  }

#pragma unroll
  for (int qt = 0; qt < 4; ++qt) {
#pragma unroll
    for (int r4 = 0; r4 < 4; ++r4) {
      float v = mx[qt][r4];
      v = fmaxf(v, __shfl_xor(v, 1));
      v = fmaxf(v, __shfl_xor(v, 2));
      v = fmaxf(v, __shfl_xor(v, 4));
      v = fmaxf(v, __shfl_xor(v, 8));
      mx[qt][r4] = v;
    }
  }
  if (lm < 4) {
    int qt = lm;
#pragma unroll
    for (int r4 = 0; r4 < 4; ++r4) {
      Mmax[w >> 1][waveQ + 16 * qt + 4 * lq + r4] = mx[qt][r4];
    }
  }
  __syncthreads();

  if (t < 128) {
    float m = fmaxf(Mmax[0][t], Mmax[1][t]);
    const float4* Qr = (const float4*)(Q + ((size_t)b * LL + q0 + t) * DD);
    float s = 0.f;
#pragma unroll
    for (int i = 0; i < 16; ++i) {
      float4 qv = Qr[i];
      s += qv.x * KsumS[4 * i] + qv.y * KsumS[4 * i + 1] + qv.z * KsumS[4 * i + 2] +
           qv.w * KsumS[4 * i + 3];
    }
    Mb[b * LL + q0 + t] = m - s * (1.0f / (float)LL);
  }
}

// ---------------------------------------------------------------------------
// Kernel 3: per-batch top-64 candidate set by Mb (set only; any order).
// ---------------------------------------------------------------------------
__global__ __launch_bounds__(256) void cand_kernel(const float* __restrict__ Mb,
                                                   int* __restrict__ cand) {
  int b = blockIdx.x, t = threadIdx.x;
  int w = t >> 6;
  float v[8];
#pragma unroll
  for (int i = 0; i < 8; ++i) v[i] = Mb[b * LL + t + 256 * i];
  __shared__ ull warr[4];
  __shared__ ull winls;
  for (int round = 0; round < CC; ++round) {
    float bv = v[0];
    int bi = 0;
#pragma unroll
    for (int i = 1; i < 8; ++i)
      if (v[i] > bv) { bv = v[i]; bi = i; }
    ull key = ((ull)fsort(bv) << 32) | (ull)(uint)(t + 256 * bi);
#pragma unroll
    for (int m = 1; m < 64; m <<= 1) {
      ull o = shfl_xor_u64(key, m);
      if (o > key) key = o;
    }
    if ((t & 63) == 0) warr[w] = key;
    __syncthreads();
    if (t == 0) {
      ull k = warr[0];
#pragma unroll
      for (int i = 1; i < 4; ++i)
        if (warr[i] > k) k = warr[i];
      winls = k;
      cand[b * CC + round] = (int)(k & 0xFFFFFFFFull);
    }
    __syncthreads();
    int wj = (int)(winls & 0xFFFFFFFFull);
    if (t == (wj & 255)) v[wj >> 8] = NEG_BIG;
  }
}

// ---------------------------------------------------------------------------
// Kernel 4: fp32 rescue partial maxes — register-tiled GEMM-max.
// ---------------------------------------------------------------------------
__global__ __launch_bounds__(256) void rescue_kernel(const float* __restrict__ Q,
                                                     const float* __restrict__ K,
                                                     const int* __restrict__ idx,
                                                     const int* __restrict__ cand,
                                                     float* __restrict__ Mpart) {
  __shared__ float Qc[64][68];    // 17408 B
  __shared__ float Kt[128][68];   // 34816 B
  __shared__ float red[64][33];   // 8448 B
  __shared__ int cidx[CC];
  int seg = blockIdx.x, b = blockIdx.y, t = threadIdx.x;

  if (t < CC) cidx[t] = cand[b * CC + t];
  __syncthreads();
  for (int li = t; li < 64 * 16; li += 256) {
    int row = li >> 4, g4 = li & 15;
    *(float4*)&Qc[row][4 * g4] =
        *(const float4*)(Q + ((size_t)b * LL + cidx[row]) * DD + 4 * g4);
  }
  for (int li = t; li < 128 * 16; li += 256) {
    int row = li >> 4, g4 = li & 15;
    int gk = idx[seg * 128 + row];
    *(float4*)&Kt[row][4 * g4] =
        *(const float4*)(K + ((size_t)b * LL + gk) * DD + 4 * g4);
  }
  __syncthreads();

  int tx = t & 7;
  int ty = t >> 3;
  float acc[8][4];
#pragma unroll
  for (int i = 0; i < 8; ++i)
#pragma unroll
    for (int j = 0; j < 4; ++j) acc[i][j] = 0.f;

#pragma unroll 4
  for (int dd = 0; dd < 64; dd += 4) {
    float4 qf[8];
#pragma unroll
    for (int i = 0; i < 8; ++i) qf[i] = *(const float4*)&Qc[tx + 8 * i][dd];
    float4 kf[4];
#pragma unroll
    for (int j = 0; j < 4; ++j) kf[j] = *(const float4*)&Kt[ty + 32 * j][dd];
#pragma unroll
    for (int i = 0; i < 8; ++i)
#pragma unroll
      for (int j = 0; j < 4; ++j) {
        float d = acc[i][j];
        d = fmaf(qf[i].x, kf[j].x, d);
        d = fmaf(qf[i].y, kf[j].y, d);
        d = fmaf(qf[i].z, kf[j].z, d);
        d = fmaf(qf[i].w, kf[j].w, d);
        acc[i][j] = d;
      }
  }

#pragma unroll
  for (int i = 0; i < 8; ++i) {
    float m = fmaxf(fmaxf(acc[i][0], acc[i][1]), fmaxf(acc[i][2], acc[i][3]));
    red[tx + 8 * i][ty] = m;
  }
  __syncthreads();
  if (t < CC) {
    float m = red[t][0];
#pragma unroll
    for (int tt = 1; tt < 32; ++tt) m = fmaxf(m, red[t][tt]);
    Mpart[((size_t)b * CC + t) * FSEG + seg] = m;
  }
}

// ---------------------------------------------------------------------------
// Kernel 5: exact fp32 M for candidates; top-40 via rank-by-counting.
// ---------------------------------------------------------------------------
__global__ __launch_bounds__(64) void select_kernel(const float* __restrict__ Q,
                                                    const float* __restrict__ Kpart,
                                                    const int* __restrict__ cand,
                                                    const float* __restrict__ Mpart,
                                                    int* __restrict__ topi) {
  int b = blockIdx.x, t = threadIdx.x;
  __shared__ float KsumS[64];
  __shared__ ull keys[CC];
  {
    float s = 0.f;
#pragma unroll
    for (int p = 0; p < 16; ++p) s += Kpart[(b * 16 + p) * 64 + t];
    KsumS[t] = s;
  }
  __syncthreads();
  int ci = cand[b * CC + t];
  float m = NEG_BIG;
#pragma unroll
  for (int s = 0; s < FSEG; ++s) m = fmaxf(m, Mpart[((size_t)b * CC + t) * FSEG + s]);
  const float4* Qr = (const float4*)(Q + ((size_t)b * LL + ci) * DD);
  float s = 0.f;
#pragma unroll
  for (int i = 0; i < 16; ++i) {
    float4 qv = Qr[i];
    s += qv.x * KsumS[4 * i] + qv.y * KsumS[4 * i + 1] + qv.z * KsumS[4 * i + 2] +
         qv.w * KsumS[4 * i + 3];
  }
  float Mf = m - s * (1.0f / (float)LL);
  ull key = ((ull)fsort(Mf) << 32) | (ull)(uint)(2047 - ci);
  keys[t] = key;
  __syncthreads();
  int rank = 0;
#pragma unroll 8
  for (int j = 0; j < CC; ++j) rank += (keys[j] > key) ? 1 : 0;
  if (rank < UU) topi[b * UU + rank] = ci;
}

// ---------------------------------------------------------------------------
// Kernel 6: FUSED epilogue per (seg, b), 128 keys/seg.
// ---------------------------------------------------------------------------
__global__ __launch_bounds__(256, 2) void fused_epilogue_kernel(
    const float* __restrict__ Q, const float* __restrict__ K,
    const float* __restrict__ V, const int* __restrict__ topi,
    float* __restrict__ scores, float* __restrict__ Opart,
    float* __restrict__ lpart) {
  int seg = blockIdx.x, b = blockIdx.y, t = threadIdx.x;
  __shared__ int cidx[UU];
  __shared__ float Qc[UU][DD];       // 10240 B
  __shared__ float pT[128 * PSTR];   // 21504 B; aliased as red[2][40][64]
  __shared__ float lw[4][20];        // 320 B

  if (t < UU) cidx[t] = topi[b * UU + t];
  __syncthreads();
  for (int li = t; li < UU * 16; li += 256) {
    int u = li >> 4, g4 = li & 15;
    *(float4*)&Qc[u][4 * g4] =
        *(const float4*)(Q + ((size_t)b * LL + cidx[u]) * DD + 4 * g4);
  }
  __syncthreads();

  int kl = t & 127, uh = t >> 7, w = t >> 6;
  int k = seg * 128 + kl;
  float4 kr[16];
  const float4* Krow = (const float4*)(K + ((size_t)b * LL + k) * DD);
#pragma unroll
  for (int i = 0; i < 16; ++i) kr[i] = Krow[i];

  float p[20];
#pragma unroll 4
  for (int j = 0; j < 20; ++j) {
    int u = uh * 20 + j;
    const float4* qp = (const float4*)&Qc[u][0];
    float s = 0.f;
#pragma unroll
    for (int i = 0; i < 16; ++i) {
      float4 qv = qp[i];  // broadcast LDS read
      s += qv.x * kr[i].x + qv.y * kr[i].y + qv.z * kr[i].z + qv.w * kr[i].w;
    }
    s *= 0.125f;
    scores[((size_t)(b * UU + u)) * LL + k] = s;
    p[j] = __expf(s);
  }

#pragma unroll
  for (int j = 0; j < 20; ++j) {
    float ls = p[j];
#pragma unroll
    for (int off = 32; off > 0; off >>= 1) ls += __shfl_xor(ls, off);
    if ((t & 63) == 0) lw[w][j] = ls;
  }
#pragma unroll
  for (int j = 0; j < 20; j += 2) {
    *(float2*)&pT[kl * PSTR + uh * 20 + j] = make_float2(p[j], p[j + 1]);
  }
  __syncthreads();
  if (t < UU) {
    int u = t;
    float ls = (u < 20) ? (lw[0][u] + lw[1][u]) : (lw[2][u - 20] + lw[3][u - 20]);
    lpart[(size_t)(b * FSEG + seg) * UU + u] = ls;
  }

  int d4 = t & 15, c = t >> 4;
  int ug = c & 7, kq = c >> 3;
  int u0 = ug * 5;
  float4 acc[5];
#pragma unroll
  for (int j = 0; j < 5; ++j) acc[j] = (float4){0.f, 0.f, 0.f, 0.f};
  const float* Vb = V + ((size_t)b * LL + seg * 128 + kq * 64) * DD;
  for (int kk = 0; kk < 64; ++kk) {
    float4 v4 = *(const float4*)(Vb + (size_t)kk * DD + 4 * d4);
    const float* prow = &pT[(kq * 64 + kk) * PSTR + u0];
#pragma unroll
    for (int j = 0; j < 5; ++j) {
      float pj = prow[j];
      acc[j].x += pj * v4.x; acc[j].y += pj * v4.y;
      acc[j].z += pj * v4.z; acc[j].w += pj * v4.w;
    }
  }
  __syncthreads();
  float* red = pT;
#pragma unroll
  for (int j = 0; j < 5; ++j)
    *(float4*)&red[(kq * 40 + u0 + j) * 64 + 4 * d4] = acc[j];
  __syncthreads();
  for (int li = t; li < UU * DD; li += 256) {
    int u = li >> 6, d = li & 63;
    float s = red[u * 64 + d] + red[(40 + u) * 64 + d];
    Opart[((size_t)(b * FSEG + seg) * UU + u) * DD + d] = s;
  }
}

// ---------------------------------------------------------------------------
// Kernel 7: combine segments: out = (sum_s Opart) / (sum_s lpart).
// ---------------------------------------------------------------------------
__global__ __launch_bounds__(256) void combine_kernel(const float* __restrict__ Opart,
                                                      const float* __restrict__ lpart,
                                                      float* __restrict__ out) {
  int b = blockIdx.x, t = threadIdx.x;
  __shared__ float Linv[UU];
  if (t < UU) {
    float Lsum = 0.f;
#pragma unroll
    for (int s = 0; s < FSEG; ++s) Lsum += lpart[(size_t)(b * FSEG + s) * UU + t];
    Linv[t] = 1.0f / Lsum;
  }
  __syncthreads();
  for (int li = t; li < UU * DD; li += 256) {
    int u = li >> 6, d = li & 63;
    float O = 0.f;
#pragma unroll
    for (int s = 0; s < FSEG; ++s)
      O += Opart[((size_t)(b * FSEG + s) * UU + u) * DD + d];
    out[((size_t)b * UU + u) * DD + d] = O * Linv[u];
  }
}

// ========================= fp32 fallback (round-2 path) ====================
__global__ __launch_bounds__(256) void ksum_kernel(const float* __restrict__ K,
                                                   const int* __restrict__ idx,
                                                   float* __restrict__ Kpart) {
  int p = blockIdx.x, b = blockIdx.y, tid = threadIdx.x;
  int d = tid & 63, c = tid >> 6;
  const float* Kb = K + (size_t)b * LL * DD;
  float acc = 0.f;
  int j0 = p * 128 + c * 32;
#pragma unroll 4
  for (int t = 0; t < 32; ++t) acc += Kb[(size_t)idx[j0 + t] * DD + d];
  __shared__ float red[256];
  red[tid] = acc;
  __syncthreads();
  if (c == 0) Kpart[(b * 16 + p) * 64 + d] = red[d] + red[64 + d] + red[128 + d] + red[192 + d];
}

__global__ __launch_bounds__(256) void m_kernel(const float* __restrict__ Q,
                                                const float* __restrict__ K,
                                                const int* __restrict__ idx,
                                                const float* __restrict__ Kpart,
                                                float* __restrict__ M) {
  __shared__ float Qs[128][68];
  __shared__ float Ks[128][68];
  __shared__ float KsumS[64];
  __shared__ float red[128][17];
  int b = blockIdx.y, q0 = blockIdx.x * 128, tid = threadIdx.x;
  int tx = tid & 15, ty = tid >> 4;
  if (tid < 64) {
    float s = 0.f;
#pragma unroll
    for (int p = 0; p < 16; ++p) s += Kpart[(b * 16 + p) * 64 + tid];
    KsumS[tid] = s;
  }
#pragma unroll
  for (int it = 0; it < 8; ++it) {
    int li = it * 256 + tid;
    int q = li >> 4, dd = (li & 15) << 2;
    *(float4*)&Qs[q][dd] = *(const float4*)(Q + ((size_t)b * LL + q0 + q) * DD + dd);
  }
  float mx[8];
#pragma unroll
  for (int i = 0; i < 8; ++i) mx[i] = NEG_BIG;
  for (int c = 0; c < LL / 128; ++c) {
    __syncthreads();
#pragma unroll
    for (int it = 0; it < 8; ++it) {
      int li = it * 256 + tid;
      int kk = li >> 4, dd = (li & 15) << 2;
      int gk = idx[c * 128 + kk];
      *(float4*)&Ks[kk][dd] = *(const float4*)(K + ((size_t)b * LL + gk) * DD + dd);
    }
    __syncthreads();
    float acc[8][8];
#pragma unroll
    for (int i = 0; i < 8; ++i)
#pragma unroll
      for (int j = 0; j < 8; ++j) acc[i][j] = 0.f;
#pragma unroll 2
    for (int dd = 0; dd < 64; dd += 4) {
      float4 qf[8];
#pragma unroll
      for (int i = 0; i < 8; ++i) qf[i] = *(const float4*)&Qs[tx + 16 * i][dd];
#pragma unroll
      for (int j = 0; j < 8; ++j) {
        float4 kf = *(const float4*)&Ks[ty + 16 * j][dd];
#pragma unroll
        for (int i = 0; i < 8; ++i)
          acc[i][j] += qf[i].x * kf.x + qf[i].y * kf.y + qf[i].z * kf.z + qf[i].w * kf.w;
      }
    }
#pragma unroll
    for (int i = 0; i < 8; ++i) {
      float m01 = fmaxf(fmaxf(acc[i][0], acc[i][1]), fmaxf(acc[i][2], acc[i][3]));
      float m23 = fmaxf(fmaxf(acc[i][4], acc[i][5]), fmaxf(acc[i][6], acc[i][7]));
      mx[i] = fmaxf(mx[i], fmaxf(m01, m23));
    }
  }
  __syncthreads();
#pragma unroll
  for (int i = 0; i < 8; ++i) red[tx + 16 * i][ty] = mx[i];
  __syncthreads();
  if (tid < 128) {
    float m = red[tid][0];
#pragma unroll
    for (int tt = 1; tt < 16; ++tt) m = fmaxf(m, red[tid][tt]);
    float s = 0.f;
#pragma unroll 16
    for (int d = 0; d < 64; ++d) s += Qs[tid][d] * KsumS[d];
    M[b * LL + q0 + tid] = m - s * (1.0f / (float)LL);
  }
}

__global__ __launch_bounds__(256) void topk_kernel(const float* __restrict__ M,
                                                   int* __restrict__ topi) {
  int b = blockIdx.x, tid = threadIdx.x;
  __shared__ float mv[LL];
  __shared__ float wv[4];
  __shared__ int wi[4];
  for (int j = tid; j < LL; j += 256) mv[j] = M[b * LL + j];
  __syncthreads();
  for (int t = 0; t < UU; ++t) {
    float bv = NEG_BIG;
    int bi = 0x7fffffff;
    for (int j = tid; j < LL; j += 256) {
      float v = mv[j];
      if (v > bv) { bv = v; bi = j; }
    }
#pragma unroll
    for (int off = 32; off > 0; off >>= 1) {
      float ov = __shfl_down(bv, off);
      int oi = __shfl_down(bi, off);
      if (ov > bv || (ov == bv && oi < bi)) { bv = ov; bi = oi; }
    }
    if ((tid & 63) == 0) { wv[tid >> 6] = bv; wi[tid >> 6] = bi; }
    __syncthreads();
    if (tid == 0) {
#pragma unroll
      for (int w = 1; w < 4; ++w)
        if (wv[w] > bv || (wv[w] == bv && wi[w] < bi)) { bv = wv[w]; bi = wi[w]; }
      topi[b * UU + t] = bi;
      mv[bi] = NEG_BIG;
    }
    __syncthreads();
  }
}

__global__ __launch_bounds__(256) void scores_kernel(const float* __restrict__ Q,
                                                     const float* __restrict__ K,
                                                     const int* __restrict__ topi,
                                                     float* __restrict__ scores) {
  int b = blockIdx.y;
  int k = blockIdx.x * 256 + threadIdx.x;
  __shared__ float Qr[UU][DD];
  for (int li = threadIdx.x; li < UU * DD; li += 256) {
    int u = li >> 6, d = li & 63;
    Qr[u][d] = Q[((size_t)b * LL + topi[b * UU + u]) * DD + d];
  }
  __syncthreads();
  float4 kr[16];
  const float4* Krow = (const float4*)(K + ((size_t)b * LL + k) * DD);
#pragma unroll
  for (int i = 0; i < 16; ++i) kr[i] = Krow[i];
  for (int u = 0; u < UU; ++u) {
    float s = 0.f;
#pragma unroll
    for (int i = 0; i < 16; ++i) {
      float4 qv = *(const float4*)&Qr[u][i << 2];
      s += qv.x * kr[i].x + qv.y * kr[i].y + qv.z * kr[i].z + qv.w * kr[i].w;
    }
    scores[((size_t)(b * UU + u)) * LL + k] = s * 0.125f;
  }
}

__global__ __launch_bounds__(256) void softmax_pv_kernel(const float* __restrict__ scores,
                                                         const float* __restrict__ V,
                                                         float* __restrict__ out) {
  int b = blockIdx.y;
  int u0 = blockIdx.x * 4;
  int tid = threadIdx.x;
  __shared__ float p[4][LL];
  __shared__ float wred[4];
  __shared__ float inv_s[4];
  __shared__ float r2[256];
#pragma unroll
  for (int uu = 0; uu < 4; ++uu) {
    const float* srow = scores + ((size_t)(b * UU + u0 + uu)) * LL;
    float m = NEG_BIG;
    for (int j = tid; j < LL; j += 256) m = fmaxf(m, srow[j]);
#pragma unroll
    for (int off = 32; off > 0; off >>= 1) m = fmaxf(m, __shfl_down(m, off));
    if ((tid & 63) == 0) wred[tid >> 6] = m;
    __syncthreads();
    float smax = fmaxf(fmaxf(wred[0], wred[1]), fmaxf(wred[2], wred[3]));
    __syncthreads();
    float ls = 0.f;
    for (int j = tid; j < LL; j += 256) {
      float e = __expf(srow[j] - smax);
      p[uu][j] = e;
      ls += e;
    }
#pragma unroll
    for (int off = 32; off > 0; off >>= 1) ls += __shfl_down(ls, off);
    if ((tid & 63) == 0) wred[tid >> 6] = ls;
    __syncthreads();
    if (tid == 0) inv_s[uu] = 1.0f / (wred[0] + wred[1] + wred[2] + wred[3]);
    __syncthreads();
  }
  int d = tid & 63, c = tid >> 6;
  float acc[4] = {0.f, 0.f, 0.f, 0.f};
  const float* Vb = V + (size_t)b * LL * DD;
  int k0 = c * (LL / 4), k1 = k0 + (LL / 4);
  for (int k = k0; k < k1; ++k) {
    float v = Vb[(size_t)k * DD + d];
#pragma unroll
    for (int uu = 0; uu < 4; ++uu) acc[uu] += p[uu][k] * v;
  }
#pragma unroll
  for (int uu = 0; uu < 4; ++uu) {
    r2[tid] = acc[uu];
    __syncthreads();
    if (c == 0) {
      out[((size_t)(b * UU) + u0 + uu) * DD + d] =
          (r2[d] + r2[64 + d] + r2[128 + d] + r2[192 + d]) * inv_s[uu];
    }
    __syncthreads();
  }
}

// ---------------------------------------------------------------------------
extern "C" void kernel_launch(void* const* d_in, const int* in_sizes, int n_in,
                              void* d_out, int out_size, void* d_ws, size_t ws_size,
                              hipStream_t stream) {
  (void)in_sizes; (void)n_in; (void)out_size;
  const float* Q = (const float*)d_in[0];
  const float* K = (const float*)d_in[1];
  const float* V = (const float*)d_in[2];
  const int* idx = (const int*)d_in[3];

  float* out = (float*)d_out;
  float* scores = out + (size_t)BB * UU * DD;

  // fast-path workspace layout (~8.7 MB)
  const size_t kg_off = 0;  // Kg bf16: 8 MB; Opart/lpart alias it after mfma_m
  const size_t kpart_off = kg_off + (size_t)BB * LL * DD * sizeof(ushort_t);
  const size_t mb_off = kpart_off + (size_t)BB * 16 * DD * sizeof(float);
  const size_t mpart_off = mb_off + (size_t)BB * LL * sizeof(float);
  const size_t cand_off = mpart_off + (size_t)BB * CC * FSEG * sizeof(float);
  const size_t topi_off = cand_off + (size_t)BB * CC * sizeof(int);
  const size_t need = topi_off + (size_t)BB * UU * sizeof(int);

  char* ws = (char*)d_ws;
  if (ws_size >= need) {
    ushort_t* Kg = (ushort_t*)(ws + kg_off);
    float* Kpart = (float*)(ws + kpart_off);
    float* Mb = (float*)(ws + mb_off);
    float* Mpart = (float*)(ws + mpart_off);
    int* cand = (int*)(ws + cand_off);
    int* topi = (int*)(ws + topi_off);
    // Opart (5.24 MB) + lpart alias the Kg region (dead after mfma_m).
    float* Opart = (float*)(ws + kg_off);
    float* lpart = Opart + (size_t)BB * FSEG * UU * DD;

    prep_ksum_kernel<<<dim3(16, BB), 256, 0, stream>>>(K, idx, Kg, Kpart);
    mfma_m_kernel<<<dim3(LL / 128, BB), 256, 0, stream>>>(Q, Kg, Kpart, Mb);
    cand_kernel<<<BB, 256, 0, stream>>>(Mb, cand);
    rescue_kernel<<<dim3(FSEG, BB), 256, 0, stream>>>(Q, K, idx, cand, Mpart);
    select_kernel<<<BB, 64, 0, stream>>>(Q, Kpart, cand, Mpart, topi);
    fused_epilogue_kernel<<<dim3(FSEG, BB), 256, 0, stream>>>(Q, K, V, topi, scores,
                                                              Opart, lpart);
    combine_kernel<<<BB, 256, 0, stream>>>(Opart, lpart, out);
  } else {
    // fp32 fallback (round-2 path), aliasing dead d_out regions
    size_t need2 =
        (size_t)(BB * LL + BB * 16 * DD) * sizeof(float) + (size_t)(BB * UU) * sizeof(int);
    float* M;
    float* Kpart;
    int* topi;
    if (ws_size >= need2) {
      M = (float*)d_ws;
      Kpart = M + BB * LL;
      topi = (int*)(Kpart + BB * 16 * DD);
    } else {
      M = scores;
      Kpart = scores + BB * LL;
      topi = (int*)out;
    }
    ksum_kernel<<<dim3(16, BB), 256, 0, stream>>>(K, idx, Kpart);
    m_kernel<<<dim3(LL / 128, BB), 256, 0, stream>>>(Q, K, idx, Kpart, M);
    topk_kernel<<<BB, 256, 0, stream>>>(M, topi);
    scores_kernel<<<dim3(LL / 256, BB), 256, 0, stream>>>(Q, K, topi, scores);
    softmax_pv_kernel<<<dim3(UU / 4, BB), 256, 0, stream>>>(scores, V, out);
  }
}

// Round 10
// 201.833 us; speedup vs baseline: 1.2187x; 1.0100x over previous
//
#include <hip/hip_runtime.h>
#include <math.h>

#define BB 32
#define LL 2048
#define DD 64
#define UU 40
#define CC 64            // bf16-phase candidates per batch
#define FSEG 16          // epilogue/rescue key segments (128 keys each)
#define PSTR2 21         // pT row stride (floats); odd -> conflict-free scalar writes
#define RSTR 68          // red row stride (floats)
#define NEG_BIG (-3.0e38f)

typedef __attribute__((ext_vector_type(8))) short short8;
typedef __attribute__((ext_vector_type(4))) float f32x4;
typedef unsigned long long ull;
typedef unsigned int uint;
typedef unsigned short ushort_t;

__device__ __forceinline__ unsigned short f2bf(float f) {
  uint u = __float_as_uint(f);
  u += 0x7FFFu + ((u >> 16) & 1u);   // RNE
  return (unsigned short)(u >> 16);
}
__device__ __forceinline__ uint fsort(float f) {
  uint u = __float_as_uint(f);
  return (u & 0x80000000u) ? ~u : (u | 0x80000000u);  // monotonic map
}
__device__ __forceinline__ ull shfl_xor_u64(ull x, int m) {
  uint lo = (uint)x, hi = (uint)(x >> 32);
  lo = __shfl_xor(lo, m);
  hi = __shfl_xor(hi, m);
  return ((ull)hi << 32) | lo;
}
__device__ __forceinline__ int4 pack_bf16x8(float4 a, float4 c4) {
  int4 o;
  o.x = (int)(f2bf(a.x) | ((uint)f2bf(a.y) << 16));
  o.y = (int)(f2bf(a.z) | ((uint)f2bf(a.w) << 16));
  o.z = (int)(f2bf(c4.x) | ((uint)f2bf(c4.y) << 16));
  o.w = (int)(f2bf(c4.z) | ((uint)f2bf(c4.w) << 16));
  return o;
}
// async 16B/lane global->LDS copy (gfx950). LDS dest = uniform base + lane*16.
__device__ __forceinline__ void async_copy16(const void* g, void* l) {
  __builtin_amdgcn_global_load_lds((const __attribute__((address_space(1))) void*)g,
                                   (__attribute__((address_space(3))) void*)l, 16, 0, 0);
}

// ---------------------------------------------------------------------------
// Kernel 1: gathered K -> bf16 Kg (PRE-SWIZZLED rows: 16B group g stored at
// slot g^(r&7)) + partial Ksum (Kpart) in one pass.
// ---------------------------------------------------------------------------
__global__ __launch_bounds__(256) void prep_ksum_kernel(const float* __restrict__ K,
                                                        const int* __restrict__ idx,
                                                        ushort_t* __restrict__ Kg,
                                                        float* __restrict__ Kpart) {
  int p = blockIdx.x, b = blockIdx.y, t = threadIdx.x;
  int g = t & 7;  // 16B group = 8 elements
  float4 sa = {0.f, 0.f, 0.f, 0.f}, sb = {0.f, 0.f, 0.f, 0.f};
#pragma unroll
  for (int it = 0; it < 4; ++it) {
    int r = p * 128 + it * 32 + (t >> 3);
    int gk = idx[r];
    const float* src = K + ((size_t)b * LL + gk) * DD + g * 8;
    float4 a = *(const float4*)src;
    float4 c4 = *(const float4*)(src + 4);
    sa.x += a.x; sa.y += a.y; sa.z += a.z; sa.w += a.w;
    sb.x += c4.x; sb.y += c4.y; sb.z += c4.z; sb.w += c4.w;
    *(int4*)(Kg + ((size_t)b * LL + r) * DD + 8 * (g ^ (r & 7))) = pack_bf16x8(a, c4);
  }
  __shared__ float red[32][64];
  int rt = t >> 3;
  *(float4*)&red[rt][g * 8] = sa;
  *(float4*)&red[rt][g * 8 + 4] = sb;
  __syncthreads();
  if (t < 64) {
    float s = 0.f;
#pragma unroll
    for (int r = 0; r < 32; ++r) s += red[r][t];
    Kpart[(b * 16 + p) * 64 + t] = s;
  }
}

// ---------------------------------------------------------------------------
// Kernel 2: bf16 MFMA M-scores (async double-buffered K staging, r9-proven).
// ---------------------------------------------------------------------------
__global__ __launch_bounds__(256) void mfma_m_kernel(const float* __restrict__ Q,
                                                     const ushort_t* __restrict__ Kg,
                                                     const float* __restrict__ Kpart,
                                                     float* __restrict__ Mb) {
  __shared__ __align__(16) ushort_t Qs[128 * 64];      // 16 KB, swizzled
  __shared__ __align__(16) ushort_t Ks[2][128 * 64];   // 2 x 16 KB, swizzled
  __shared__ float Mmax[2][128];
  __shared__ float KsumS[64];

  int b = blockIdx.y, q0 = blockIdx.x * 128;
  int t = threadIdx.x;
  int w = t >> 6, L = t & 63;

  const ushort_t* KgB = Kg + (size_t)b * LL * DD;

  // issue chunk 0 async into Ks[0] (flies during Ksum + Q staging)
#pragma unroll
  for (int i = 0; i < 4; ++i) {
    const ushort_t* gp =
        KgB + (size_t)(w * 32 + i * 8 + (L >> 3)) * DD + (L & 7) * 8;
    async_copy16(gp, &Ks[0][(w * 32 + i * 8) * 64]);
  }

  if (t < 64) {
    float s = 0.f;
#pragma unroll
    for (int p = 0; p < 16; ++p) s += Kpart[(b * 16 + p) * 64 + t];
    KsumS[t] = s;
  }

  // stage Q tile once: read fp32, convert to bf16, swizzled store
  {
    int g = t & 7;
#pragma unroll
    for (int it = 0; it < 4; ++it) {
      int r = it * 32 + (t >> 3);
      const float* src = Q + ((size_t)b * LL + q0 + r) * DD + g * 8;
      float4 a = *(const float4*)src;
      float4 c4 = *(const float4*)(src + 4);
      *(int4*)&Qs[r * 64 + 8 * (g ^ (r & 7))] = pack_bf16x8(a, c4);
    }
  }
  __syncthreads();  // drains chunk-0 DMA + Q staging

  f32x4 mx[4];
#pragma unroll
  for (int i = 0; i < 4; ++i) mx[i] = (f32x4){NEG_BIG, NEG_BIG, NEG_BIG, NEG_BIG};

  const int waveQ = 64 * (w & 1);
  const int waveK = 64 * (w >> 1);
  const int lm = L & 15;
  const int lq = L >> 4;

  for (int c = 0; c < LL / 128; ++c) {
    int cur = c & 1;
    if (c < LL / 128 - 1) {
      int nxt = cur ^ 1;
#pragma unroll
      for (int i = 0; i < 4; ++i) {
        const ushort_t* gp =
            KgB + (size_t)((c + 1) * 128 + w * 32 + i * 8 + (L >> 3)) * DD + (L & 7) * 8;
        async_copy16(gp, &Ks[nxt][(w * 32 + i * 8) * 64]);
      }
    }

    f32x4 acc[4][4];
#pragma unroll
    for (int i = 0; i < 4; ++i)
#pragma unroll
      for (int j = 0; j < 4; ++j) acc[i][j] = (f32x4){0.f, 0.f, 0.f, 0.f};

#pragma unroll
    for (int s = 0; s < 2; ++s) {
      int g = 4 * s + lq;
      short8 A[4];
#pragma unroll
      for (int qt = 0; qt < 4; ++qt) {
        int r = waveQ + 16 * qt + lm;
        A[qt] = *(const short8*)&Qs[r * 64 + 8 * (g ^ (r & 7))];
      }
#pragma unroll
      for (int kt = 0; kt < 4; ++kt) {
        int rB = waveK + 16 * kt + lm;
        short8 Bf = *(const short8*)&Ks[cur][rB * 64 + 8 * (g ^ (rB & 7))];
#pragma unroll
        for (int qt = 0; qt < 4; ++qt) {
          acc[qt][kt] = __builtin_amdgcn_mfma_f32_16x16x32_bf16(A[qt], Bf, acc[qt][kt], 0, 0, 0);
        }
      }
    }
#pragma unroll
    for (int qt = 0; qt < 4; ++qt)
#pragma unroll
      for (int kt = 0; kt < 4; ++kt) {
#pragma unroll
        for (int r4 = 0; r4 < 4; ++r4) mx[qt][r4] = fmaxf(mx[qt][r4], acc[qt][kt][r4]);
      }
    __syncthreads();  // drains next-chunk DMA; protects cur buf for overwrite
  }

#pragma unroll
  for (int qt = 0; qt < 4; ++qt) {
#pragma unroll
    for (int r4 = 0; r4 < 4; ++r4) {
      float v = mx[qt][r4];
      v = fmaxf(v, __shfl_xor(v, 1));
      v = fmaxf(v, __shfl_xor(v, 2));
      v = fmaxf(v, __shfl_xor(v, 4));
      v = fmaxf(v, __shfl_xor(v, 8));
      mx[qt][r4] = v;
    }
  }
  if (lm < 4) {
    int qt = lm;
#pragma unroll
    for (int r4 = 0; r4 < 4; ++r4) {
      Mmax[w >> 1][waveQ + 16 * qt + 4 * lq + r4] = mx[qt][r4];
    }
  }
  __syncthreads();

  if (t < 128) {
    float m = fmaxf(Mmax[0][t], Mmax[1][t]);
    const float4* Qr = (const float4*)(Q + ((size_t)b * LL + q0 + t) * DD);
    float s = 0.f;
#pragma unroll
    for (int i = 0; i < 16; ++i) {
      float4 qv = Qr[i];
      s += qv.x * KsumS[4 * i] + qv.y * KsumS[4 * i + 1] + qv.z * KsumS[4 * i + 2] +
           qv.w * KsumS[4 * i + 3];
    }
    Mb[b * LL + q0 + t] = m - s * (1.0f / (float)LL);
  }
}

// ---------------------------------------------------------------------------
// Kernel 3: per-batch top-64 candidate set by Mb (set only; any order).
// ---------------------------------------------------------------------------
__global__ __launch_bounds__(256) void cand_kernel(const float* __restrict__ Mb,
                                                   int* __restrict__ cand) {
  int b = blockIdx.x, t = threadIdx.x;
  int w = t >> 6;
  float v[8];
#pragma unroll
  for (int i = 0; i < 8; ++i) v[i] = Mb[b * LL + t + 256 * i];
  __shared__ ull warr[4];
  __shared__ ull winls;
  for (int round = 0; round < CC; ++round) {
    float bv = v[0];
    int bi = 0;
#pragma unroll
    for (int i = 1; i < 8; ++i)
      if (v[i] > bv) { bv = v[i]; bi = i; }
    ull key = ((ull)fsort(bv) << 32) | (ull)(uint)(t + 256 * bi);
#pragma unroll
    for (int m = 1; m < 64; m <<= 1) {
      ull o = shfl_xor_u64(key, m);
      if (o > key) key = o;
    }
    if ((t & 63) == 0) warr[w] = key;
    __syncthreads();
    if (t == 0) {
      ull k = warr[0];
#pragma unroll
      for (int i = 1; i < 4; ++i)
        if (warr[i] > k) k = warr[i];
      winls = k;
      cand[b * CC + round] = (int)(k & 0xFFFFFFFFull);
    }
    __syncthreads();
    int wj = (int)(winls & 0xFFFFFFFFull);
    if (t == (wj & 255)) v[wj >> 8] = NEG_BIG;
  }
}

// ---------------------------------------------------------------------------
// Kernel 4: fp32 rescue partial maxes — register-tiled GEMM-max (r7-proven).
// ---------------------------------------------------------------------------
__global__ __launch_bounds__(256) void rescue_kernel(const float* __restrict__ Q,
                                                     const float* __restrict__ K,
                                                     const int* __restrict__ idx,
                                                     const int* __restrict__ cand,
                                                     float* __restrict__ Mpart) {
  __shared__ float Qc[64][68];    // 17408 B
  __shared__ float Kt[128][68];   // 34816 B
  __shared__ float red[64][33];   // 8448 B
  __shared__ int cidx[CC];
  int seg = blockIdx.x, b = blockIdx.y, t = threadIdx.x;

  if (t < CC) cidx[t] = cand[b * CC + t];
  __syncthreads();
  for (int li = t; li < 64 * 16; li += 256) {
    int row = li >> 4, g4 = li & 15;
    *(float4*)&Qc[row][4 * g4] =
        *(const float4*)(Q + ((size_t)b * LL + cidx[row]) * DD + 4 * g4);
  }
  for (int li = t; li < 128 * 16; li += 256) {
    int row = li >> 4, g4 = li & 15;
    int gk = idx[seg * 128 + row];
    *(float4*)&Kt[row][4 * g4] =
        *(const float4*)(K + ((size_t)b * LL + gk) * DD + 4 * g4);
  }
  __syncthreads();

  int tx = t & 7;
  int ty = t >> 3;
  float acc[8][4];
#pragma unroll
  for (int i = 0; i < 8; ++i)
#pragma unroll
    for (int j = 0; j < 4; ++j) acc[i][j] = 0.f;

#pragma unroll 4
  for (int dd = 0; dd < 64; dd += 4) {
    float4 qf[8];
#pragma unroll
    for (int i = 0; i < 8; ++i) qf[i] = *(const float4*)&Qc[tx + 8 * i][dd];
    float4 kf[4];
#pragma unroll
    for (int j = 0; j < 4; ++j) kf[j] = *(const float4*)&Kt[ty + 32 * j][dd];
#pragma unroll
    for (int i = 0; i < 8; ++i)
#pragma unroll
      for (int j = 0; j < 4; ++j) {
        float d = acc[i][j];
        d = fmaf(qf[i].x, kf[j].x, d);
        d = fmaf(qf[i].y, kf[j].y, d);
        d = fmaf(qf[i].z, kf[j].z, d);
        d = fmaf(qf[i].w, kf[j].w, d);
        acc[i][j] = d;
      }
  }

#pragma unroll
  for (int i = 0; i < 8; ++i) {
    float m = fmaxf(fmaxf(acc[i][0], acc[i][1]), fmaxf(acc[i][2], acc[i][3]));
    red[tx + 8 * i][ty] = m;
  }
  __syncthreads();
  if (t < CC) {
    float m = red[t][0];
#pragma unroll
    for (int tt = 1; tt < 32; ++tt) m = fmaxf(m, red[t][tt]);
    Mpart[((size_t)b * CC + t) * FSEG + seg] = m;
  }
}

// ---------------------------------------------------------------------------
// Kernel 5: exact fp32 M for candidates; top-40 via rank-by-counting.
// ---------------------------------------------------------------------------
__global__ __launch_bounds__(64) void select_kernel(const float* __restrict__ Q,
                                                    const float* __restrict__ Kpart,
                                                    const int* __restrict__ cand,
                                                    const float* __restrict__ Mpart,
                                                    int* __restrict__ topi) {
  int b = blockIdx.x, t = threadIdx.x;
  __shared__ float KsumS[64];
  __shared__ ull keys[CC];
  {
    float s = 0.f;
#pragma unroll
    for (int p = 0; p < 16; ++p) s += Kpart[(b * 16 + p) * 64 + t];
    KsumS[t] = s;
  }
  __syncthreads();
  int ci = cand[b * CC + t];
  float m = NEG_BIG;
#pragma unroll
  for (int s = 0; s < FSEG; ++s) m = fmaxf(m, Mpart[((size_t)b * CC + t) * FSEG + s]);
  const float4* Qr = (const float4*)(Q + ((size_t)b * LL + ci) * DD);
  float s = 0.f;
#pragma unroll
  for (int i = 0; i < 16; ++i) {
    float4 qv = Qr[i];
    s += qv.x * KsumS[4 * i] + qv.y * KsumS[4 * i + 1] + qv.z * KsumS[4 * i + 2] +
         qv.w * KsumS[4 * i + 3];
  }
  float Mf = m - s * (1.0f / (float)LL);
  ull key = ((ull)fsort(Mf) << 32) | (ull)(uint)(2047 - ci);
  keys[t] = key;
  __syncthreads();
  int rank = 0;
#pragma unroll 8
  for (int j = 0; j < CC; ++j) rank += (keys[j] > key) ? 1 : 0;
  if (rank < UU) topi[b * UU + rank] = ci;
}

// ---------------------------------------------------------------------------
// Kernel 6: FUSED epilogue per (seg, uhalf, b): block = 128 keys x 20 u.
// grid 1024 = 4 blocks/CU (was grid-limited at 2). Thread owns 2 keys x 5 u:
// K streamed from global (2 float4/iter), Q broadcast from LDS (reused
// across both keys -> 4x fewer ds_read_b128 than r9). lpart via pure wave
// shuffle (wave = all 64 kp = the block's full 128 keys for its u-group).
// Per-(u,k) dot expression order unchanged -> scores bit-identical.
// ---------------------------------------------------------------------------
__global__ __launch_bounds__(256, 2) void fused_epilogue_kernel(
    const float* __restrict__ Q, const float* __restrict__ K,
    const float* __restrict__ V, const int* __restrict__ topi,
    float* __restrict__ scores, float* __restrict__ Opart,
    float* __restrict__ lpart) {
  int bx = blockIdx.x;              // 0..31
  int seg = bx >> 1, uh2 = bx & 1;  // 16 segs x 2 u-halves
  int b = blockIdx.y, t = threadIdx.x;
  __shared__ int cidx[20];
  __shared__ float Qc[20][DD];        // 5120 B
  __shared__ float pTred[4 * 20 * RSTR];  // 21760 B: pT[128][21] / red[4][20][RSTR]

  if (t < 20) cidx[t] = topi[b * UU + uh2 * 20 + t];
  __syncthreads();
  for (int li = t; li < 20 * 16; li += 256) {
    int u = li >> 4, g4 = li & 15;
    *(float4*)&Qc[u][4 * g4] =
        *(const float4*)(Q + ((size_t)b * LL + cidx[u]) * DD + 4 * g4);
  }
  __syncthreads();

  float* pT = pTred;

  // ---- Phase A: kp = t&63 -> keys k0, k0+64; ug = t>>6 -> u's ug*5..ug*5+4
  int kp = t & 63, ug = t >> 6;
  int u0 = ug * 5;
  int k0 = seg * 128 + kp;
  const float4* K0 = (const float4*)(K + ((size_t)b * LL + k0) * DD);
  const float4* K1 = (const float4*)(K + ((size_t)b * LL + k0 + 64) * DD);
  float s0[5] = {0.f, 0.f, 0.f, 0.f, 0.f};
  float s1[5] = {0.f, 0.f, 0.f, 0.f, 0.f};
#pragma unroll
  for (int i = 0; i < 16; ++i) {
    float4 ka = K0[i];
    float4 kb = K1[i];
#pragma unroll
    for (int j = 0; j < 5; ++j) {
      float4 qv = *(const float4*)&Qc[u0 + j][4 * i];  // wave-broadcast LDS read
      s0[j] += qv.x * ka.x + qv.y * ka.y + qv.z * ka.z + qv.w * ka.w;
      s1[j] += qv.x * kb.x + qv.y * kb.y + qv.z * kb.z + qv.w * kb.w;
    }
  }

  float p0[5], p1[5];
#pragma unroll
  for (int j = 0; j < 5; ++j) {
    float sa = s0[j] * 0.125f, sb = s1[j] * 0.125f;
    int u = uh2 * 20 + u0 + j;
    scores[((size_t)(b * UU + u)) * LL + k0] = sa;
    scores[((size_t)(b * UU + u)) * LL + k0 + 64] = sb;
    p0[j] = __expf(sa);
    p1[j] = __expf(sb);
  }

  // ---- Phase B: wave-level exp sums (wave covers all 128 keys for its 5 u)
#pragma unroll
  for (int j = 0; j < 5; ++j) {
    float ls = p0[j] + p1[j];
#pragma unroll
    for (int off = 32; off > 0; off >>= 1) ls += __shfl_xor(ls, off);
    if (kp == 0)
      lpart[(size_t)(b * FSEG + seg) * UU + uh2 * 20 + u0 + j] = ls;
  }
  // transpose p into pT[key-local][20] (stride 21: odd -> conflict-free)
#pragma unroll
  for (int j = 0; j < 5; ++j) {
    pT[kp * PSTR2 + u0 + j] = p0[j];
    pT[(kp + 64) * PSTR2 + u0 + j] = p1[j];
  }
  __syncthreads();

  // ---- Phase C: d4 = t&15, c = t>>4; ug3 = c&3 -> 5 u, kq = c>>2 -> 32 keys
  int d4 = t & 15, c = t >> 4;
  int ug3 = c & 3, kq = c >> 2;
  int uu0 = ug3 * 5;
  float4 acc[5];
#pragma unroll
  for (int j = 0; j < 5; ++j) acc[j] = (float4){0.f, 0.f, 0.f, 0.f};
  const float* Vb = V + ((size_t)b * LL + seg * 128 + kq * 32) * DD;
  for (int kk = 0; kk < 32; ++kk) {
    float4 v4 = *(const float4*)(Vb + (size_t)kk * DD + 4 * d4);
    const float* prow = &pT[(kq * 32 + kk) * PSTR2 + uu0];
#pragma unroll
    for (int j = 0; j < 5; ++j) {
      float pj = prow[j];
      acc[j].x += pj * v4.x; acc[j].y += pj * v4.y;
      acc[j].z += pj * v4.z; acc[j].w += pj * v4.w;
    }
  }
  __syncthreads();  // all pT reads done before aliasing as red
  float* red = pTred;  // red[(kq*20+u)*RSTR + d]
#pragma unroll
  for (int j = 0; j < 5; ++j)
    *(float4*)&red[(kq * 20 + uu0 + j) * RSTR + 4 * d4] = acc[j];
  __syncthreads();
  for (int li = t; li < 20 * DD; li += 256) {
    int u = li >> 6, d = li & 63;
    float s = red[(0 * 20 + u) * RSTR + d] + red[(1 * 20 + u) * RSTR + d] +
              red[(2 * 20 + u) * RSTR + d] + red[(3 * 20 + u) * RSTR + d];
    Opart[((size_t)(b * FSEG + seg) * UU + uh2 * 20 + u) * DD + d] = s;
  }
}

// ---------------------------------------------------------------------------
// Kernel 7: combine segments: out = (sum_s Opart) / (sum_s lpart).
// ---------------------------------------------------------------------------
__global__ __launch_bounds__(256) void combine_kernel(const float* __restrict__ Opart,
                                                      const float* __restrict__ lpart,
                                                      float* __restrict__ out) {
  int b = blockIdx.x, t = threadIdx.x;
  __shared__ float Linv[UU];
  if (t < UU) {
    float Lsum = 0.f;
#pragma unroll
    for (int s = 0; s < FSEG; ++s) Lsum += lpart[(size_t)(b * FSEG + s) * UU + t];
    Linv[t] = 1.0f / Lsum;
  }
  __syncthreads();
  for (int li = t; li < UU * DD; li += 256) {
    int u = li >> 6, d = li & 63;
    float O = 0.f;
#pragma unroll
    for (int s = 0; s < FSEG; ++s)
      O += Opart[((size_t)(b * FSEG + s) * UU + u) * DD + d];
    out[((size_t)b * UU + u) * DD + d] = O * Linv[u];
  }
}

// ========================= fp32 fallback (round-2 path) ====================
__global__ __launch_bounds__(256) void ksum_kernel(const float* __restrict__ K,
                                                   const int* __restrict__ idx,
                                                   float* __restrict__ Kpart) {
  int p = blockIdx.x, b = blockIdx.y, tid = threadIdx.x;
  int d = tid & 63, c = tid >> 6;
  const float* Kb = K + (size_t)b * LL * DD;
  float acc = 0.f;
  int j0 = p * 128 + c * 32;
#pragma unroll 4
  for (int t = 0; t < 32; ++t) acc += Kb[(size_t)idx[j0 + t] * DD + d];
  __shared__ float red[256];
  red[tid] = acc;
  __syncthreads();
  if (c == 0) Kpart[(b * 16 + p) * 64 + d] = red[d] + red[64 + d] + red[128 + d] + red[192 + d];
}

__global__ __launch_bounds__(256) void m_kernel(const float* __restrict__ Q,
                                                const float* __restrict__ K,
                                                const int* __restrict__ idx,
                                                const float* __restrict__ Kpart,
                                                float* __restrict__ M) {
  __shared__ float Qs[128][68];
  __shared__ float Ks[128][68];
  __shared__ float KsumS[64];
  __shared__ float red[128][17];
  int b = blockIdx.y, q0 = blockIdx.x * 128, tid = threadIdx.x;
  int tx = tid & 15, ty = tid >> 4;
  if (tid < 64) {
    float s = 0.f;
#pragma unroll
    for (int p = 0; p < 16; ++p) s += Kpart[(b * 16 + p) * 64 + tid];
    KsumS[tid] = s;
  }
#pragma unroll
  for (int it = 0; it < 8; ++it) {
    int li = it * 256 + tid;
    int q = li >> 4, dd = (li & 15) << 2;
    *(float4*)&Qs[q][dd] = *(const float4*)(Q + ((size_t)b * LL + q0 + q) * DD + dd);
  }
  float mx[8];
#pragma unroll
  for (int i = 0; i < 8; ++i) mx[i] = NEG_BIG;
  for (int c = 0; c < LL / 128; ++c) {
    __syncthreads();
#pragma unroll
    for (int it = 0; it < 8; ++it) {
      int li = it * 256 + tid;
      int kk = li >> 4, dd = (li & 15) << 2;
      int gk = idx[c * 128 + kk];
      *(float4*)&Ks[kk][dd] = *(const float4*)(K + ((size_t)b * LL + gk) * DD + dd);
    }
    __syncthreads();
    float acc[8][8];
#pragma unroll
    for (int i = 0; i < 8; ++i)
#pragma unroll
      for (int j = 0; j < 8; ++j) acc[i][j] = 0.f;
#pragma unroll 2
    for (int dd = 0; dd < 64; dd += 4) {
      float4 qf[8];
#pragma unroll
      for (int i = 0; i < 8; ++i) qf[i] = *(const float4*)&Qs[tx + 16 * i][dd];
#pragma unroll
      for (int j = 0; j < 8; ++j) {
        float4 kf = *(const float4*)&Ks[ty + 16 * j][dd];
#pragma unroll
        for (int i = 0; i < 8; ++i)
          acc[i][j] += qf[i].x * kf.x + qf[i].y * kf.y + qf[i].z * kf.z + qf[i].w * kf.w;
      }
    }
#pragma unroll
    for (int i = 0; i < 8; ++i) {
      float m01 = fmaxf(fmaxf(acc[i][0], acc[i][1]), fmaxf(acc[i][2], acc[i][3]));
      float m23 = fmaxf(fmaxf(acc[i][4], acc[i][5]), fmaxf(acc[i][6], acc[i][7]));
      mx[i] = fmaxf(mx[i], fmaxf(m01, m23));
    }
  }
  __syncthreads();
#pragma unroll
  for (int i = 0; i < 8; ++i) red[tx + 16 * i][ty] = mx[i];
  __syncthreads();
  if (tid < 128) {
    float m = red[tid][0];
#pragma unroll
    for (int tt = 1; tt < 16; ++tt) m = fmaxf(m, red[tid][tt]);
    float s = 0.f;
#pragma unroll 16
    for (int d = 0; d < 64; ++d) s += Qs[tid][d] * KsumS[d];
    M[b * LL + q0 + tid] = m - s * (1.0f / (float)LL);
  }
}

__global__ __launch_bounds__(256) void topk_kernel(const float* __restrict__ M,
                                                   int* __restrict__ topi) {
  int b = blockIdx.x, tid = threadIdx.x;
  __shared__ float mv[LL];
  __shared__ float wv[4];
  __shared__ int wi[4];
  for (int j = tid; j < LL; j += 256) mv[j] = M[b * LL + j];
  __syncthreads();
  for (int t = 0; t < UU; ++t) {
    float bv = NEG_BIG;
    int bi = 0x7fffffff;
    for (int j = tid; j < LL; j += 256) {
      float v = mv[j];
      if (v > bv) { bv = v; bi = j; }
    }
#pragma unroll
    for (int off = 32; off > 0; off >>= 1) {
      float ov = __shfl_down(bv, off);
      int oi = __shfl_down(bi, off);
      if (ov > bv || (ov == bv && oi < bi)) { bv = ov; bi = oi; }
    }
    if ((tid & 63) == 0) { wv[tid >> 6] = bv; wi[tid >> 6] = bi; }
    __syncthreads();
    if (tid == 0) {
#pragma unroll
      for (int w = 1; w < 4; ++w)
        if (wv[w] > bv || (wv[w] == bv && wi[w] < bi)) { bv = wv[w]; bi = wi[w]; }
      topi[b * UU + t] = bi;
      mv[bi] = NEG_BIG;
    }
    __syncthreads();
  }
}

__global__ __launch_bounds__(256) void scores_kernel(const float* __restrict__ Q,
                                                     const float* __restrict__ K,
                                                     const int* __restrict__ topi,
                                                     float* __restrict__ scores) {
  int b = blockIdx.y;
  int k = blockIdx.x * 256 + threadIdx.x;
  __shared__ float Qr[UU][DD];
  for (int li = threadIdx.x; li < UU * DD; li += 256) {
    int u = li >> 6, d = li & 63;
    Qr[u][d] = Q[((size_t)b * LL + topi[b * UU + u]) * DD + d];
  }
  __syncthreads();
  float4 kr[16];
  const float4* Krow = (const float4*)(K + ((size_t)b * LL + k) * DD);
#pragma unroll
  for (int i = 0; i < 16; ++i) kr[i] = Krow[i];
  for (int u = 0; u < UU; ++u) {
    float s = 0.f;
#pragma unroll
    for (int i = 0; i < 16; ++i) {
      float4 qv = *(const float4*)&Qr[u][i << 2];
      s += qv.x * kr[i].x + qv.y * kr[i].y + qv.z * kr[i].z + qv.w * kr[i].w;
    }
    scores[((size_t)(b * UU + u)) * LL + k] = s * 0.125f;
  }
}

__global__ __launch_bounds__(256) void softmax_pv_kernel(const float* __restrict__ scores,
                                                         const float* __restrict__ V,
                                                         float* __restrict__ out) {
  int b = blockIdx.y;
  int u0 = blockIdx.x * 4;
  int tid = threadIdx.x;
  __shared__ float p[4][LL];
  __shared__ float wred[4];
  __shared__ float inv_s[4];
  __shared__ float r2[256];
#pragma unroll
  for (int uu = 0; uu < 4; ++uu) {
    const float* srow = scores + ((size_t)(b * UU + u0 + uu)) * LL;
    float m = NEG_BIG;
    for (int j = tid; j < LL; j += 256) m = fmaxf(m, srow[j]);
#pragma unroll
    for (int off = 32; off > 0; off >>= 1) m = fmaxf(m, __shfl_down(m, off));
    if ((tid & 63) == 0) wred[tid >> 6] = m;
    __syncthreads();
    float smax = fmaxf(fmaxf(wred[0], wred[1]), fmaxf(wred[2], wred[3]));
    __syncthreads();
    float ls = 0.f;
    for (int j = tid; j < LL; j += 256) {
      float e = __expf(srow[j] - smax);
      p[uu][j] = e;
      ls += e;
    }
#pragma unroll
    for (int off = 32; off > 0; off >>= 1) ls += __shfl_down(ls, off);
    if ((tid & 63) == 0) wred[tid >> 6] = ls;
    __syncthreads();
    if (tid == 0) inv_s[uu] = 1.0f / (wred[0] + wred[1] + wred[2] + wred[3]);
    __syncthreads();
  }
  int d = tid & 63, c = tid >> 6;
  float acc[4] = {0.f, 0.f, 0.f, 0.f};
  const float* Vb = V + (size_t)b * LL * DD;
  int k0 = c * (LL / 4), k1 = k0 + (LL / 4);
  for (int k = k0; k < k1; ++k) {
    float v = Vb[(size_t)k * DD + d];
#pragma unroll
    for (int uu = 0; uu < 4; ++uu) acc[uu] += p[uu][k] * v;
  }
#pragma unroll
  for (int uu = 0; uu < 4; ++uu) {
    r2[tid] = acc[uu];
    __syncthreads();
    if (c == 0) {
      out[((size_t)(b * UU) + u0 + uu) * DD + d] =
          (r2[d] + r2[64 + d] + r2[128 + d] + r2[192 + d]) * inv_s[uu];
    }
    __syncthreads();
  }
}

// ---------------------------------------------------------------------------
extern "C" void kernel_launch(void* const* d_in, const int* in_sizes, int n_in,
                              void* d_out, int out_size, void* d_ws, size_t ws_size,
                              hipStream_t stream) {
  (void)in_sizes; (void)n_in; (void)out_size;
  const float* Q = (const float*)d_in[0];
  const float* K = (const float*)d_in[1];
  const float* V = (const float*)d_in[2];
  const int* idx = (const int*)d_in[3];

  float* out = (float*)d_out;
  float* scores = out + (size_t)BB * UU * DD;

  // fast-path workspace layout (~8.7 MB)
  const size_t kg_off = 0;  // Kg bf16: 8 MB; Opart/lpart alias it after mfma_m
  const size_t kpart_off = kg_off + (size_t)BB * LL * DD * sizeof(ushort_t);
  const size_t mb_off = kpart_off + (size_t)BB * 16 * DD * sizeof(float);
  const size_t mpart_off = mb_off + (size_t)BB * LL * sizeof(float);
  const size_t cand_off = mpart_off + (size_t)BB * CC * FSEG * sizeof(float);
  const size_t topi_off = cand_off + (size_t)BB * CC * sizeof(int);
  const size_t need = topi_off + (size_t)BB * UU * sizeof(int);

  char* ws = (char*)d_ws;
  if (ws_size >= need) {
    ushort_t* Kg = (ushort_t*)(ws + kg_off);
    float* Kpart = (float*)(ws + kpart_off);
    float* Mb = (float*)(ws + mb_off);
    float* Mpart = (float*)(ws + mpart_off);
    int* cand = (int*)(ws + cand_off);
    int* topi = (int*)(ws + topi_off);
    // Opart (5.24 MB) + lpart alias the Kg region (dead after mfma_m).
    float* Opart = (float*)(ws + kg_off);
    float* lpart = Opart + (size_t)BB * FSEG * UU * DD;

    prep_ksum_kernel<<<dim3(16, BB), 256, 0, stream>>>(K, idx, Kg, Kpart);
    mfma_m_kernel<<<dim3(LL / 128, BB), 256, 0, stream>>>(Q, Kg, Kpart, Mb);
    cand_kernel<<<BB, 256, 0, stream>>>(Mb, cand);
    rescue_kernel<<<dim3(FSEG, BB), 256, 0, stream>>>(Q, K, idx, cand, Mpart);
    select_kernel<<<BB, 64, 0, stream>>>(Q, Kpart, cand, Mpart, topi);
    fused_epilogue_kernel<<<dim3(FSEG * 2, BB), 256, 0, stream>>>(Q, K, V, topi, scores,
                                                                  Opart, lpart);
    combine_kernel<<<BB, 256, 0, stream>>>(Opart, lpart, out);
  } else {
    // fp32 fallback (round-2 path), aliasing dead d_out regions
    size_t need2 =
        (size_t)(BB * LL + BB * 16 * DD) * sizeof(float) + (size_t)(BB * UU) * sizeof(int);
    float* M;
    float* Kpart;
    int* topi;
    if (ws_size >= need2) {
      M = (float*)d_ws;
      Kpart = M + BB * LL;
      topi = (int*)(Kpart + BB * 16 * DD);
    } else {
      M = scores;
      Kpart = scores + BB * LL;
      topi = (int*)out;
    }
    ksum_kernel<<<dim3(16, BB), 256, 0, stream>>>(K, idx, Kpart);
    m_kernel<<<dim3(LL / 128, BB), 256, 0, stream>>>(Q, K, idx, Kpart, M);
    topk_kernel<<<BB, 256, 0, stream>>>(M, topi);
    scores_kernel<<<dim3(LL / 256, BB), 256, 0, stream>>>(Q, K, topi, scores);
    softmax_pv_kernel<<<dim3(UU / 4, BB), 256, 0, stream>>>(scores, V, out);
  }
}